// Round 10
// baseline (131.424 us; speedup 1.0000x reference)
//
#include <hip/hip_runtime.h>

#define LOG2E  1.44269504088896f
#define NLOG2E (-1.44269504088896f)
#define LN2    0.693147180559945f

// DPP move: returns src value permuted by ctrl (full masks, bound_ctrl=0-fill)
template <int CTRL>
__device__ __forceinline__ float dpp_mov(float x) {
    return __int_as_float(__builtin_amdgcn_update_dpp(
        0, __float_as_int(x), CTRL, 0xF, 0xF, true));
}
// quad_perm: xor1=[1,0,3,2]=0xB1, xor2=[2,3,0,1]=0x4E; row_ror:4=0x124, row_ror:8=0x128

// lane-halves butterfly adds on the VALU pipe (gfx950 permlane*_swap); DS fallback
__device__ __forceinline__ float xor16_add(float x) {
#if __has_builtin(__builtin_amdgcn_permlane16_swap)
    auto sw = __builtin_amdgcn_permlane16_swap(__float_as_int(x), __float_as_int(x),
                                               false, false);
    return __int_as_float(sw[0]) + __int_as_float(sw[1]);
#else
    return x + __shfl_xor(x, 16, 64);
#endif
}
__device__ __forceinline__ float xor32_add(float x) {
#if __has_builtin(__builtin_amdgcn_permlane32_swap)
    auto sw = __builtin_amdgcn_permlane32_swap(__float_as_int(x), __float_as_int(x),
                                               false, false);
    return __int_as_float(sw[0]) + __int_as_float(sw[1]);
#else
    return x + __shfl_xor(x, 32, 64);
#endif
}

// ---------- W_h [H,D] -> W_t [D,H] (pre-scaled by `scale`) ----------
__global__ void transpose_kernel(const float* __restrict__ Wh,
                                 float* __restrict__ Wt, int Hn, int Dn,
                                 float scale) {
    __shared__ float tile[32][33];
    int tx = threadIdx.x;        // 0..31
    int ty = threadIdx.y;        // 0..7
    int i0 = blockIdx.x * 32;    // D tile origin
    int h0 = blockIdx.y * 32;    // H tile origin
#pragma unroll
    for (int k = 0; k < 4; ++k)
        tile[ty + 8 * k][tx] = scale * Wh[(size_t)(h0 + ty + 8 * k) * Dn + (i0 + tx)];
    __syncthreads();
#pragma unroll
    for (int k = 0; k < 4; ++k)
        Wt[(size_t)(i0 + ty + 8 * k) * Hn + (h0 + tx)] = tile[tx][ty + 8 * k];
}

// ---------- pass 1: per-chunk partial x·W sums (8 waves share weight stream) ----
template <int HN, int LN>
__global__ __launch_bounds__(512) void partial_kernel(
    const float* __restrict__ x, const float* __restrict__ Wt,
    float* __restrict__ partial, int Dn, int Bn, int C)
{
    const int wid  = threadIdx.x >> 6;
    const int lane = threadIdx.x & 63;
    const int bpc  = Bn / 8;         // b-groups per c
    const int c    = blockIdx.x / bpc;
    const int b    = (blockIdx.x % bpc) * 8 + wid;   // 8 waves: same c, adjacent b

    const float* wp = Wt + (size_t)(c * LN) * HN + lane * 4;
    const float* xp = x  + (size_t)b * Dn + c * LN;

    float4 acc = make_float4(0.f, 0.f, 0.f, 0.f);
#pragma unroll 2
    for (int ii = 0; ii < LN; ii += 4) {
        const float4 x4 = *(const float4*)(xp + ii);
        const float4 w0 = *(const float4*)(wp);
        const float4 w1 = *(const float4*)(wp + HN);
        const float4 w2 = *(const float4*)(wp + 2 * HN);
        const float4 w3 = *(const float4*)(wp + 3 * HN);
        wp += 4 * HN;
        acc.x = fmaf(x4.x, w0.x, fmaf(x4.y, w1.x, fmaf(x4.z, w2.x, fmaf(x4.w, w3.x, acc.x))));
        acc.y = fmaf(x4.x, w0.y, fmaf(x4.y, w1.y, fmaf(x4.z, w2.y, fmaf(x4.w, w3.y, acc.y))));
        acc.z = fmaf(x4.x, w0.z, fmaf(x4.y, w1.z, fmaf(x4.z, w2.z, fmaf(x4.w, w3.z, acc.z))));
        acc.w = fmaf(x4.x, w0.w, fmaf(x4.y, w1.w, fmaf(x4.z, w2.w, fmaf(x4.w, w3.w, acc.w))));
    }
    *(float4*)(partial + ((size_t)b * C + c) * HN + lane * 4) = acc;
}

// ---------- pass 2: exclusive scan over chunks (in place) ----------
__global__ __launch_bounds__(256) void scan_kernel(
    float* __restrict__ partial, int Hn, int C)
{
    const int b    = blockIdx.x * 4 + (threadIdx.x >> 6);
    const int lane = threadIdx.x & 63;
    float* base = partial + (size_t)b * C * Hn + lane * 4;
    float4 acc = make_float4(0.f, 0.f, 0.f, 0.f);
    for (int c = 0; c < C; ++c) {
        float4 cur = *(float4*)(base + (size_t)c * Hn);
        *(float4*)(base + (size_t)c * Hn) = acc;
        acc.x += cur.x; acc.y += cur.y; acc.z += cur.z; acc.w += cur.w;
    }
}

// ---------- pass 3: main NADE chunk kernel (8 waves share weight stream) ----
// Scaled domain: Wt2 = -log2e * W^T, prefix likewise, bh2 = -log2e * b_h.
// sigma_h = rcp(1 + exp2(u_h));  u += xv*w + bh2 per step.
// Block = 512 threads = 8 waves, ALL at the same chunk c with b = base..base+7:
// the 8 waves stream the SAME 2KB/iter aw/Wt2 window -> L1-shared (1 L2 miss,
// 7 L1 hits), vs R9's c-major layout where co-resident blocks had disjoint
// streams and every weight load was an L2 round-trip.
template <int HN, int LN>
__global__ __launch_bounds__(512) void nade_main(
    const float* __restrict__ x,      // [B,D]
    const float* __restrict__ Wt2,    // [D,H] transposed, scaled
    const float* __restrict__ prefix, // [B,C,H] exclusive prefix, scaled
    const float* __restrict__ bh,     // [H] (unscaled)
    const float* __restrict__ aw,     // [D,H]
    const float* __restrict__ ab,     // [D]
    float* __restrict__ llp,          // [B,C] partial log-likelihoods
    int Dn, int Bn, int C)
{
    const int wid  = threadIdx.x >> 6;
    const int lane = threadIdx.x & 63;
    const int bpc  = Bn / 8;
    const int c    = blockIdx.x / bpc;
    const int b    = (blockIdx.x % bpc) * 8 + wid;   // 8 waves: same c, adjacent b
    const int j    = lane & 3;       // this lane's i-class within a 4-batch

    float4 bh2 = *(const float4*)(bh + lane * 4);
    bh2.x *= NLOG2E; bh2.y *= NLOG2E; bh2.z *= NLOG2E; bh2.w *= NLOG2E;

    float4 u = *(const float4*)(prefix + ((size_t)b * C + c) * HN + lane * 4);
    const float cl = (float)(c * LN);
    u.x = fmaf(cl, bh2.x, u.x); u.y = fmaf(cl, bh2.y, u.y);
    u.z = fmaf(cl, bh2.z, u.z); u.w = fmaf(cl, bh2.w, u.w);

    const int lo = lane * 4;
    const float* awp = aw  + (size_t)(c * LN) * HN + lo;
    const float* wp  = Wt2 + (size_t)(c * LN) * HN + lo;
    const float* xp  = x   + (size_t)b * Dn + c * LN;
    const float* abp = ab  + c * LN;

    float A  = 0.f;                  // sum of lp*(2*x-1) over my i-class
    float Bs = 0.f;                  // sum of x over my i-class

#pragma unroll 2
    for (int ii = 0; ii < LN; ii += 4) {
        // ================= batch load phase (constexpr offsets) =============
        const float4 a0 = *(const float4*)(awp);
        const float4 a1 = *(const float4*)(awp + HN);
        const float4 a2 = *(const float4*)(awp + 2 * HN);
        const float4 a3 = *(const float4*)(awp + 3 * HN);
        const float4 w0 = *(const float4*)(wp);
        const float4 w1 = *(const float4*)(wp + HN);
        const float4 w2 = *(const float4*)(wp + 2 * HN);
        const float4 w3 = *(const float4*)(wp + 3 * HN);
        const float4 x4  = *(const float4*)(xp + ii);    // wave-uniform
        const float4 ab4 = *(const float4*)(abp + ii);   // wave-uniform
        awp += 4 * HN;
        wp  += 4 * HN;

        // per-lane class values via static select (no DS)
        const float t0x = (j & 1) ? x4.y  : x4.x;
        const float t1x = (j & 1) ? x4.w  : x4.z;
        const float xq  = (j & 2) ? t1x   : t0x;
        const float t0a = (j & 1) ? ab4.y : ab4.x;
        const float t1a = (j & 1) ? ab4.w : ab4.z;
        const float abq = (j & 2) ? t1a   : t0a;

        // ================= compute phase ====================================
        float p0, p1, p2, p3;
        {   // m = 0 (sigmoid BEFORE update: exclusive prefix)
            const float s0 = __builtin_amdgcn_rcpf(1.0f + __builtin_amdgcn_exp2f(u.x));
            const float s1 = __builtin_amdgcn_rcpf(1.0f + __builtin_amdgcn_exp2f(u.y));
            const float s2 = __builtin_amdgcn_rcpf(1.0f + __builtin_amdgcn_exp2f(u.z));
            const float s3 = __builtin_amdgcn_rcpf(1.0f + __builtin_amdgcn_exp2f(u.w));
            p0 = fmaf(a0.w, s3, fmaf(a0.z, s2, fmaf(a0.y, s1, a0.x * s0)));
            u.x += fmaf(x4.x, w0.x, bh2.x); u.y += fmaf(x4.x, w0.y, bh2.y);
            u.z += fmaf(x4.x, w0.z, bh2.z); u.w += fmaf(x4.x, w0.w, bh2.w);
        }
        {   // m = 1
            const float s0 = __builtin_amdgcn_rcpf(1.0f + __builtin_amdgcn_exp2f(u.x));
            const float s1 = __builtin_amdgcn_rcpf(1.0f + __builtin_amdgcn_exp2f(u.y));
            const float s2 = __builtin_amdgcn_rcpf(1.0f + __builtin_amdgcn_exp2f(u.z));
            const float s3 = __builtin_amdgcn_rcpf(1.0f + __builtin_amdgcn_exp2f(u.w));
            p1 = fmaf(a1.w, s3, fmaf(a1.z, s2, fmaf(a1.y, s1, a1.x * s0)));
            u.x += fmaf(x4.y, w1.x, bh2.x); u.y += fmaf(x4.y, w1.y, bh2.y);
            u.z += fmaf(x4.y, w1.z, bh2.z); u.w += fmaf(x4.y, w1.w, bh2.w);
        }
        {   // m = 2
            const float s0 = __builtin_amdgcn_rcpf(1.0f + __builtin_amdgcn_exp2f(u.x));
            const float s1 = __builtin_amdgcn_rcpf(1.0f + __builtin_amdgcn_exp2f(u.y));
            const float s2 = __builtin_amdgcn_rcpf(1.0f + __builtin_amdgcn_exp2f(u.z));
            const float s3 = __builtin_amdgcn_rcpf(1.0f + __builtin_amdgcn_exp2f(u.w));
            p2 = fmaf(a2.w, s3, fmaf(a2.z, s2, fmaf(a2.y, s1, a2.x * s0)));
            u.x += fmaf(x4.z, w2.x, bh2.x); u.y += fmaf(x4.z, w2.y, bh2.y);
            u.z += fmaf(x4.z, w2.z, bh2.z); u.w += fmaf(x4.z, w2.w, bh2.w);
        }
        {   // m = 3
            const float s0 = __builtin_amdgcn_rcpf(1.0f + __builtin_amdgcn_exp2f(u.x));
            const float s1 = __builtin_amdgcn_rcpf(1.0f + __builtin_amdgcn_exp2f(u.y));
            const float s2 = __builtin_amdgcn_rcpf(1.0f + __builtin_amdgcn_exp2f(u.z));
            const float s3 = __builtin_amdgcn_rcpf(1.0f + __builtin_amdgcn_exp2f(u.w));
            p3 = fmaf(a3.w, s3, fmaf(a3.z, s2, fmaf(a3.y, s1, a3.x * s0)));
            u.x += fmaf(x4.w, w3.x, bh2.x); u.y += fmaf(x4.w, w3.y, bh2.y);
            u.z += fmaf(x4.w, w3.z, bh2.z); u.w += fmaf(x4.w, w3.w, bh2.w);
        }

        // ======= reduce: DPP quad + select + DPP row + permlane swaps =======
        p0 += dpp_mov<0xB1>(p0); p0 += dpp_mov<0x4E>(p0);
        p1 += dpp_mov<0xB1>(p1); p1 += dpp_mov<0x4E>(p1);
        p2 += dpp_mov<0xB1>(p2); p2 += dpp_mov<0x4E>(p2);
        p3 += dpp_mov<0xB1>(p3); p3 += dpp_mov<0x4E>(p3);
        const float tq0 = (lane & 1) ? p1 : p0;
        const float tq1 = (lane & 1) ? p3 : p2;
        float q = (lane & 2) ? tq1 : tq0;
        q += dpp_mov<0x124>(q);          // row_ror:4  (sum quads in row)
        q += dpp_mov<0x128>(q);          // row_ror:8
        q = xor16_add(q);                // cross-row, VALU pipe
        q = xor32_add(q);
        // q = full 256-h dot for i = c*LN + ii + j (replicated per class)
        const float s = q + abq;
        const float lp = -LN2 *
            __builtin_amdgcn_logf(1.0f + __builtin_amdgcn_exp2f(-s * LOG2E));
        A = fmaf(lp, fmaf(2.0f, xq, -1.0f), A);
        Bs += xq;
    }

    // each class replicated 16x across the wave
#pragma unroll
    for (int off = 32; off > 0; off >>= 1) {
        A  += __shfl_xor(A, off, 64);
        Bs += __shfl_xor(Bs, off, 64);
    }
    if (lane == 0)
        llp[(size_t)b * C + c] = (A - Bs) * (1.0f / 16.0f) + (float)LN;
}

// ---------- pass 4: final reduce ----------
__global__ void final_kernel(const float* __restrict__ llp,
                             float* __restrict__ out, int Bn, int C) {
    const int b = blockIdx.x * blockDim.x + threadIdx.x;
    if (b < Bn) {
        float s = 0.f;
        for (int c = 0; c < C; ++c) s += llp[(size_t)b * C + c];
        out[b] = s;
    }
}

// ---------- fallback (round-1 style, unscaled) ----------
__global__ __launch_bounds__(64) void nade_fallback(
    const float* __restrict__ x, const float* __restrict__ Wh,
    const float* __restrict__ bh, const float* __restrict__ aw,
    const float* __restrict__ ab, float* __restrict__ out, int Dn, int Hn)
{
    const int b    = blockIdx.x;
    const int lane = threadIdx.x;
    const float* xrow = x + (size_t)b * Dn;
    float ll = 0.f;
    float accl[8];
    float bhl[8];
    for (int k = 0; k < 8; ++k) { accl[k] = 0.f; bhl[k] = 0.f; }
    const int hper = Hn / 64;
    for (int k = 0; k < hper && k < 8; ++k) bhl[k] = bh[lane * hper + k];
    for (int i = 0; i < Dn; ++i) {
        float pm = 0.f;
        for (int k = 0; k < hper && k < 8; ++k) {
            const int h = lane * hper + k;
            const float sg = __builtin_amdgcn_rcpf(
                1.0f + __builtin_amdgcn_exp2f(-accl[k] * LOG2E));
            pm = fmaf(aw[(size_t)i * Hn + h], sg, pm);
        }
        for (int off = 32; off > 0; off >>= 1) pm += __shfl_xor(pm, off, 64);
        const float s = pm + ab[i];
        const float lp = -LN2 *
            __builtin_amdgcn_logf(1.0f + __builtin_amdgcn_exp2f(-s * LOG2E));
        const float xv = xrow[i];
        ll += xv * lp + (1.0f - xv) * (1.0f - lp);
        for (int k = 0; k < hper && k < 8; ++k) {
            const int h = lane * hper + k;
            accl[k] = fmaf(xv, Wh[(size_t)h * Dn + i], accl[k]) + bhl[k];
        }
    }
    if (lane == 0) out[b] = ll;
}

extern "C" void kernel_launch(void* const* d_in, const int* in_sizes, int n_in,
                              void* d_out, int out_size, void* d_ws, size_t ws_size,
                              hipStream_t stream) {
    const float* x  = (const float*)d_in[0];
    const float* Wh = (const float*)d_in[1];
    const float* bh = (const float*)d_in[2];
    const float* aw = (const float*)d_in[3];
    const float* ab = (const float*)d_in[4];
    float* out = (float*)d_out;

    const int Bn = out_size;          // 1024
    const int Hn = in_sizes[2];       // 256
    const int Dn = in_sizes[4];       // 1024
    constexpr int HN = 256;
    constexpr int LN = 128;
    const int C = 8;

    const size_t wt_bytes  = (size_t)Dn * Hn * sizeof(float);
    const size_t pf_bytes  = (size_t)Bn * C * Hn * sizeof(float);
    const size_t llp_bytes = (size_t)Bn * C * sizeof(float);

    const bool shapes_ok = (Hn == HN) && (Dn == C * LN) && (Bn % 8 == 0);
    const bool full_path = shapes_ok && ws_size >= wt_bytes + pf_bytes + llp_bytes;

    if (full_path) {
        float* Wt2    = (float*)d_ws;
        float* prefix = (float*)((char*)d_ws + wt_bytes);
        float* llp    = (float*)((char*)d_ws + wt_bytes + pf_bytes);

        transpose_kernel<<<dim3(Dn / 32, Hn / 32), dim3(32, 8), 0, stream>>>(
            Wh, Wt2, Hn, Dn, NLOG2E);
        partial_kernel<HN, LN><<<(Bn / 8) * C, 512, 0, stream>>>(
            x, Wt2, prefix, Dn, Bn, C);
        scan_kernel<<<Bn / 4, 256, 0, stream>>>(prefix, Hn, C);
        nade_main<HN, LN><<<(Bn / 8) * C, 512, 0, stream>>>(
            x, Wt2, prefix, bh, aw, ab, llp, Dn, Bn, C);
        final_kernel<<<(Bn + 255) / 256, 256, 0, stream>>>(llp, out, Bn, C);
    } else {
        nade_fallback<<<Bn, 64, 0, stream>>>(x, Wh, bh, aw, ab, out, Dn, Hn);
    }
}

// Round 11
// 116.916 us; speedup vs baseline: 1.1241x; 1.1241x over previous
//
#include <hip/hip_runtime.h>

#define LOG2E  1.44269504088896f
#define NLOG2E (-1.44269504088896f)
#define LN2    0.693147180559945f

// DPP move: returns src value permuted by ctrl (full masks, bound_ctrl=0-fill)
template <int CTRL>
__device__ __forceinline__ float dpp_mov(float x) {
    return __int_as_float(__builtin_amdgcn_update_dpp(
        0, __float_as_int(x), CTRL, 0xF, 0xF, true));
}
// quad_perm: xor1=[1,0,3,2]=0xB1, xor2=[2,3,0,1]=0x4E; row_ror:4=0x124, row_ror:8=0x128

// lane-halves butterfly adds on the VALU pipe (gfx950 permlane*_swap); DS fallback
__device__ __forceinline__ float xor16_add(float x) {
#if __has_builtin(__builtin_amdgcn_permlane16_swap)
    auto sw = __builtin_amdgcn_permlane16_swap(__float_as_int(x), __float_as_int(x),
                                               false, false);
    return __int_as_float(sw[0]) + __int_as_float(sw[1]);
#else
    return x + __shfl_xor(x, 16, 64);
#endif
}
__device__ __forceinline__ float xor32_add(float x) {
#if __has_builtin(__builtin_amdgcn_permlane32_swap)
    auto sw = __builtin_amdgcn_permlane32_swap(__float_as_int(x), __float_as_int(x),
                                               false, false);
    return __int_as_float(sw[0]) + __int_as_float(sw[1]);
#else
    return x + __shfl_xor(x, 32, 64);
#endif
}

// ---------- W_h [H,D] -> W_t [D,H] (pre-scaled by `scale`) ----------
__global__ void transpose_kernel(const float* __restrict__ Wh,
                                 float* __restrict__ Wt, int Hn, int Dn,
                                 float scale) {
    __shared__ float tile[32][33];
    int tx = threadIdx.x;        // 0..31
    int ty = threadIdx.y;        // 0..7
    int i0 = blockIdx.x * 32;    // D tile origin
    int h0 = blockIdx.y * 32;    // H tile origin
#pragma unroll
    for (int k = 0; k < 4; ++k)
        tile[ty + 8 * k][tx] = scale * Wh[(size_t)(h0 + ty + 8 * k) * Dn + (i0 + tx)];
    __syncthreads();
#pragma unroll
    for (int k = 0; k < 4; ++k)
        Wt[(size_t)(i0 + ty + 8 * k) * Hn + (h0 + tx)] = tile[tx][ty + 8 * k];
}

// ---------- pass 1: per-chunk partial x·W sums, 4 batch rows per wave ----------
// Each wave loads the weight row-window ONCE and applies it to 4 b-rows:
// load:FMA ratio 4x better than 1-b; ILP (64 indep FMA) hides L2 latency.
template <int HN, int LN>
__global__ __launch_bounds__(512) void partial_kernel(
    const float* __restrict__ x, const float* __restrict__ Wt,
    float* __restrict__ partial, int Dn, int Bn, int C)
{
    const int wid  = threadIdx.x >> 6;
    const int lane = threadIdx.x & 63;
    const int gpc  = Bn / 32;        // b-groups (of 32) per c
    const int c    = blockIdx.x / gpc;
    const int b0   = (blockIdx.x % gpc) * 32 + wid * 4;  // 4 b's per wave

    const float* wp  = Wt + (size_t)(c * LN) * HN + lane * 4;
    const float* xp0 = x + (size_t)(b0 + 0) * Dn + c * LN;
    const float* xp1 = x + (size_t)(b0 + 1) * Dn + c * LN;
    const float* xp2 = x + (size_t)(b0 + 2) * Dn + c * LN;
    const float* xp3 = x + (size_t)(b0 + 3) * Dn + c * LN;

    float4 ac0 = make_float4(0.f, 0.f, 0.f, 0.f);
    float4 ac1 = make_float4(0.f, 0.f, 0.f, 0.f);
    float4 ac2 = make_float4(0.f, 0.f, 0.f, 0.f);
    float4 ac3 = make_float4(0.f, 0.f, 0.f, 0.f);

#pragma unroll 2
    for (int ii = 0; ii < LN; ii += 4) {
        const float4 w0 = *(const float4*)(wp);
        const float4 w1 = *(const float4*)(wp + HN);
        const float4 w2 = *(const float4*)(wp + 2 * HN);
        const float4 w3 = *(const float4*)(wp + 3 * HN);
        const float4 xa = *(const float4*)(xp0 + ii);   // wave-uniform
        const float4 xb = *(const float4*)(xp1 + ii);
        const float4 xc = *(const float4*)(xp2 + ii);
        const float4 xd = *(const float4*)(xp3 + ii);
        wp += 4 * HN;

        ac0.x = fmaf(xa.x, w0.x, fmaf(xa.y, w1.x, fmaf(xa.z, w2.x, fmaf(xa.w, w3.x, ac0.x))));
        ac0.y = fmaf(xa.x, w0.y, fmaf(xa.y, w1.y, fmaf(xa.z, w2.y, fmaf(xa.w, w3.y, ac0.y))));
        ac0.z = fmaf(xa.x, w0.z, fmaf(xa.y, w1.z, fmaf(xa.z, w2.z, fmaf(xa.w, w3.z, ac0.z))));
        ac0.w = fmaf(xa.x, w0.w, fmaf(xa.y, w1.w, fmaf(xa.z, w2.w, fmaf(xa.w, w3.w, ac0.w))));

        ac1.x = fmaf(xb.x, w0.x, fmaf(xb.y, w1.x, fmaf(xb.z, w2.x, fmaf(xb.w, w3.x, ac1.x))));
        ac1.y = fmaf(xb.x, w0.y, fmaf(xb.y, w1.y, fmaf(xb.z, w2.y, fmaf(xb.w, w3.y, ac1.y))));
        ac1.z = fmaf(xb.x, w0.z, fmaf(xb.y, w1.z, fmaf(xb.z, w2.z, fmaf(xb.w, w3.z, ac1.z))));
        ac1.w = fmaf(xb.x, w0.w, fmaf(xb.y, w1.w, fmaf(xb.z, w2.w, fmaf(xb.w, w3.w, ac1.w))));

        ac2.x = fmaf(xc.x, w0.x, fmaf(xc.y, w1.x, fmaf(xc.z, w2.x, fmaf(xc.w, w3.x, ac2.x))));
        ac2.y = fmaf(xc.x, w0.y, fmaf(xc.y, w1.y, fmaf(xc.z, w2.y, fmaf(xc.w, w3.y, ac2.y))));
        ac2.z = fmaf(xc.x, w0.z, fmaf(xc.y, w1.z, fmaf(xc.z, w2.z, fmaf(xc.w, w3.z, ac2.z))));
        ac2.w = fmaf(xc.x, w0.w, fmaf(xc.y, w1.w, fmaf(xc.z, w2.w, fmaf(xc.w, w3.w, ac2.w))));

        ac3.x = fmaf(xd.x, w0.x, fmaf(xd.y, w1.x, fmaf(xd.z, w2.x, fmaf(xd.w, w3.x, ac3.x))));
        ac3.y = fmaf(xd.x, w0.y, fmaf(xd.y, w1.y, fmaf(xd.z, w2.y, fmaf(xd.w, w3.y, ac3.y))));
        ac3.z = fmaf(xd.x, w0.z, fmaf(xd.y, w1.z, fmaf(xd.z, w2.z, fmaf(xd.w, w3.z, ac3.z))));
        ac3.w = fmaf(xd.x, w0.w, fmaf(xd.y, w1.w, fmaf(xd.z, w2.w, fmaf(xd.w, w3.w, ac3.w))));
    }

    float* outp = partial + ((size_t)b0 * C + c) * HN + lane * 4;
    *(float4*)(outp)                      = ac0;
    *(float4*)(outp + (size_t)C * HN)     = ac1;
    *(float4*)(outp + (size_t)2 * C * HN) = ac2;
    *(float4*)(outp + (size_t)3 * C * HN) = ac3;
}

// ---------- pass 2: exclusive scan over chunks (in place) ----------
__global__ __launch_bounds__(256) void scan_kernel(
    float* __restrict__ partial, int Hn, int C)
{
    const int b    = blockIdx.x * 4 + (threadIdx.x >> 6);
    const int lane = threadIdx.x & 63;
    float* base = partial + (size_t)b * C * Hn + lane * 4;
    float4 acc = make_float4(0.f, 0.f, 0.f, 0.f);
    for (int c = 0; c < C; ++c) {
        float4 cur = *(float4*)(base + (size_t)c * Hn);
        *(float4*)(base + (size_t)c * Hn) = acc;
        acc.x += cur.x; acc.y += cur.y; acc.z += cur.z; acc.w += cur.w;
    }
}

// ---------- pass 3: main NADE chunk kernel (8 waves share weight stream) ----
// Scaled domain: Wt2 = -log2e * W^T, prefix likewise, bh2 = -log2e * b_h.
// sigma_h = rcp(1 + exp2(u_h));  u += xv*w + bh2 per step.
template <int HN, int LN>
__global__ __launch_bounds__(512) void nade_main(
    const float* __restrict__ x,      // [B,D]
    const float* __restrict__ Wt2,    // [D,H] transposed, scaled
    const float* __restrict__ prefix, // [B,C,H] exclusive prefix, scaled
    const float* __restrict__ bh,     // [H] (unscaled)
    const float* __restrict__ aw,     // [D,H]
    const float* __restrict__ ab,     // [D]
    float* __restrict__ llp,          // [B,C] partial log-likelihoods
    int Dn, int Bn, int C)
{
    const int wid  = threadIdx.x >> 6;
    const int lane = threadIdx.x & 63;
    const int bpc  = Bn / 8;
    const int c    = blockIdx.x / bpc;
    const int b    = (blockIdx.x % bpc) * 8 + wid;   // 8 waves: same c, adjacent b
    const int j    = lane & 3;       // this lane's i-class within a 4-batch

    float4 bh2 = *(const float4*)(bh + lane * 4);
    bh2.x *= NLOG2E; bh2.y *= NLOG2E; bh2.z *= NLOG2E; bh2.w *= NLOG2E;

    float4 u = *(const float4*)(prefix + ((size_t)b * C + c) * HN + lane * 4);
    const float cl = (float)(c * LN);
    u.x = fmaf(cl, bh2.x, u.x); u.y = fmaf(cl, bh2.y, u.y);
    u.z = fmaf(cl, bh2.z, u.z); u.w = fmaf(cl, bh2.w, u.w);

    const int lo = lane * 4;
    const float* awp = aw  + (size_t)(c * LN) * HN + lo;
    const float* wp  = Wt2 + (size_t)(c * LN) * HN + lo;
    const float* xp  = x   + (size_t)b * Dn + c * LN;
    const float* abp = ab  + c * LN;

    float A  = 0.f;                  // sum of lp*(2*x-1) over my i-class
    float Bs = 0.f;                  // sum of x over my i-class

#pragma unroll 2
    for (int ii = 0; ii < LN; ii += 4) {
        // ================= batch load phase (constexpr offsets) =============
        const float4 a0 = *(const float4*)(awp);
        const float4 a1 = *(const float4*)(awp + HN);
        const float4 a2 = *(const float4*)(awp + 2 * HN);
        const float4 a3 = *(const float4*)(awp + 3 * HN);
        const float4 w0 = *(const float4*)(wp);
        const float4 w1 = *(const float4*)(wp + HN);
        const float4 w2 = *(const float4*)(wp + 2 * HN);
        const float4 w3 = *(const float4*)(wp + 3 * HN);
        const float4 x4  = *(const float4*)(xp + ii);    // wave-uniform
        const float4 ab4 = *(const float4*)(abp + ii);   // wave-uniform
        awp += 4 * HN;
        wp  += 4 * HN;

        // per-lane class values via static select (no DS)
        const float t0x = (j & 1) ? x4.y  : x4.x;
        const float t1x = (j & 1) ? x4.w  : x4.z;
        const float xq  = (j & 2) ? t1x   : t0x;
        const float t0a = (j & 1) ? ab4.y : ab4.x;
        const float t1a = (j & 1) ? ab4.w : ab4.z;
        const float abq = (j & 2) ? t1a   : t0a;

        // ================= compute phase ====================================
        float p0, p1, p2, p3;
        {   // m = 0 (sigmoid BEFORE update: exclusive prefix)
            const float s0 = __builtin_amdgcn_rcpf(1.0f + __builtin_amdgcn_exp2f(u.x));
            const float s1 = __builtin_amdgcn_rcpf(1.0f + __builtin_amdgcn_exp2f(u.y));
            const float s2 = __builtin_amdgcn_rcpf(1.0f + __builtin_amdgcn_exp2f(u.z));
            const float s3 = __builtin_amdgcn_rcpf(1.0f + __builtin_amdgcn_exp2f(u.w));
            p0 = fmaf(a0.w, s3, fmaf(a0.z, s2, fmaf(a0.y, s1, a0.x * s0)));
            u.x += fmaf(x4.x, w0.x, bh2.x); u.y += fmaf(x4.x, w0.y, bh2.y);
            u.z += fmaf(x4.x, w0.z, bh2.z); u.w += fmaf(x4.x, w0.w, bh2.w);
        }
        {   // m = 1
            const float s0 = __builtin_amdgcn_rcpf(1.0f + __builtin_amdgcn_exp2f(u.x));
            const float s1 = __builtin_amdgcn_rcpf(1.0f + __builtin_amdgcn_exp2f(u.y));
            const float s2 = __builtin_amdgcn_rcpf(1.0f + __builtin_amdgcn_exp2f(u.z));
            const float s3 = __builtin_amdgcn_rcpf(1.0f + __builtin_amdgcn_exp2f(u.w));
            p1 = fmaf(a1.w, s3, fmaf(a1.z, s2, fmaf(a1.y, s1, a1.x * s0)));
            u.x += fmaf(x4.y, w1.x, bh2.x); u.y += fmaf(x4.y, w1.y, bh2.y);
            u.z += fmaf(x4.y, w1.z, bh2.z); u.w += fmaf(x4.y, w1.w, bh2.w);
        }
        {   // m = 2
            const float s0 = __builtin_amdgcn_rcpf(1.0f + __builtin_amdgcn_exp2f(u.x));
            const float s1 = __builtin_amdgcn_rcpf(1.0f + __builtin_amdgcn_exp2f(u.y));
            const float s2 = __builtin_amdgcn_rcpf(1.0f + __builtin_amdgcn_exp2f(u.z));
            const float s3 = __builtin_amdgcn_rcpf(1.0f + __builtin_amdgcn_exp2f(u.w));
            p2 = fmaf(a2.w, s3, fmaf(a2.z, s2, fmaf(a2.y, s1, a2.x * s0)));
            u.x += fmaf(x4.z, w2.x, bh2.x); u.y += fmaf(x4.z, w2.y, bh2.y);
            u.z += fmaf(x4.z, w2.z, bh2.z); u.w += fmaf(x4.z, w2.w, bh2.w);
        }
        {   // m = 3
            const float s0 = __builtin_amdgcn_rcpf(1.0f + __builtin_amdgcn_exp2f(u.x));
            const float s1 = __builtin_amdgcn_rcpf(1.0f + __builtin_amdgcn_exp2f(u.y));
            const float s2 = __builtin_amdgcn_rcpf(1.0f + __builtin_amdgcn_exp2f(u.z));
            const float s3 = __builtin_amdgcn_rcpf(1.0f + __builtin_amdgcn_exp2f(u.w));
            p3 = fmaf(a3.w, s3, fmaf(a3.z, s2, fmaf(a3.y, s1, a3.x * s0)));
            u.x += fmaf(x4.w, w3.x, bh2.x); u.y += fmaf(x4.w, w3.y, bh2.y);
            u.z += fmaf(x4.w, w3.z, bh2.z); u.w += fmaf(x4.w, w3.w, bh2.w);
        }

        // ======= reduce: DPP quad + select + DPP row + permlane swaps =======
        p0 += dpp_mov<0xB1>(p0); p0 += dpp_mov<0x4E>(p0);
        p1 += dpp_mov<0xB1>(p1); p1 += dpp_mov<0x4E>(p1);
        p2 += dpp_mov<0xB1>(p2); p2 += dpp_mov<0x4E>(p2);
        p3 += dpp_mov<0xB1>(p3); p3 += dpp_mov<0x4E>(p3);
        const float tq0 = (lane & 1) ? p1 : p0;
        const float tq1 = (lane & 1) ? p3 : p2;
        float q = (lane & 2) ? tq1 : tq0;
        q += dpp_mov<0x124>(q);          // row_ror:4  (sum quads in row)
        q += dpp_mov<0x128>(q);          // row_ror:8
        q = xor16_add(q);                // cross-row, VALU pipe
        q = xor32_add(q);
        // q = full 256-h dot for i = c*LN + ii + j (replicated per class)
        const float s = q + abq;
        const float lp = -LN2 *
            __builtin_amdgcn_logf(1.0f + __builtin_amdgcn_exp2f(-s * LOG2E));
        A = fmaf(lp, fmaf(2.0f, xq, -1.0f), A);
        Bs += xq;
    }

    // each class replicated 16x across the wave
#pragma unroll
    for (int off = 32; off > 0; off >>= 1) {
        A  += __shfl_xor(A, off, 64);
        Bs += __shfl_xor(Bs, off, 64);
    }
    if (lane == 0)
        llp[(size_t)b * C + c] = (A - Bs) * (1.0f / 16.0f) + (float)LN;
}

// ---------- pass 4: final reduce ----------
__global__ void final_kernel(const float* __restrict__ llp,
                             float* __restrict__ out, int Bn, int C) {
    const int b = blockIdx.x * blockDim.x + threadIdx.x;
    if (b < Bn) {
        float s = 0.f;
        for (int c = 0; c < C; ++c) s += llp[(size_t)b * C + c];
        out[b] = s;
    }
}

// ---------- fallback (round-1 style, unscaled) ----------
__global__ __launch_bounds__(64) void nade_fallback(
    const float* __restrict__ x, const float* __restrict__ Wh,
    const float* __restrict__ bh, const float* __restrict__ aw,
    const float* __restrict__ ab, float* __restrict__ out, int Dn, int Hn)
{
    const int b    = blockIdx.x;
    const int lane = threadIdx.x;
    const float* xrow = x + (size_t)b * Dn;
    float ll = 0.f;
    float accl[8];
    float bhl[8];
    for (int k = 0; k < 8; ++k) { accl[k] = 0.f; bhl[k] = 0.f; }
    const int hper = Hn / 64;
    for (int k = 0; k < hper && k < 8; ++k) bhl[k] = bh[lane * hper + k];
    for (int i = 0; i < Dn; ++i) {
        float pm = 0.f;
        for (int k = 0; k < hper && k < 8; ++k) {
            const int h = lane * hper + k;
            const float sg = __builtin_amdgcn_rcpf(
                1.0f + __builtin_amdgcn_exp2f(-accl[k] * LOG2E));
            pm = fmaf(aw[(size_t)i * Hn + h], sg, pm);
        }
        for (int off = 32; off > 0; off >>= 1) pm += __shfl_xor(pm, off, 64);
        const float s = pm + ab[i];
        const float lp = -LN2 *
            __builtin_amdgcn_logf(1.0f + __builtin_amdgcn_exp2f(-s * LOG2E));
        const float xv = xrow[i];
        ll += xv * lp + (1.0f - xv) * (1.0f - lp);
        for (int k = 0; k < hper && k < 8; ++k) {
            const int h = lane * hper + k;
            accl[k] = fmaf(xv, Wh[(size_t)h * Dn + i], accl[k]) + bhl[k];
        }
    }
    if (lane == 0) out[b] = ll;
}

extern "C" void kernel_launch(void* const* d_in, const int* in_sizes, int n_in,
                              void* d_out, int out_size, void* d_ws, size_t ws_size,
                              hipStream_t stream) {
    const float* x  = (const float*)d_in[0];
    const float* Wh = (const float*)d_in[1];
    const float* bh = (const float*)d_in[2];
    const float* aw = (const float*)d_in[3];
    const float* ab = (const float*)d_in[4];
    float* out = (float*)d_out;

    const int Bn = out_size;          // 1024
    const int Hn = in_sizes[2];       // 256
    const int Dn = in_sizes[4];       // 1024
    constexpr int HN = 256;
    constexpr int LN = 128;
    const int C = 8;

    const size_t wt_bytes  = (size_t)Dn * Hn * sizeof(float);
    const size_t pf_bytes  = (size_t)Bn * C * Hn * sizeof(float);
    const size_t llp_bytes = (size_t)Bn * C * sizeof(float);

    const bool shapes_ok = (Hn == HN) && (Dn == C * LN) && (Bn % 32 == 0);
    const bool full_path = shapes_ok && ws_size >= wt_bytes + pf_bytes + llp_bytes;

    if (full_path) {
        float* Wt2    = (float*)d_ws;
        float* prefix = (float*)((char*)d_ws + wt_bytes);
        float* llp    = (float*)((char*)d_ws + wt_bytes + pf_bytes);

        transpose_kernel<<<dim3(Dn / 32, Hn / 32), dim3(32, 8), 0, stream>>>(
            Wh, Wt2, Hn, Dn, NLOG2E);
        partial_kernel<HN, LN><<<(Bn / 32) * C, 512, 0, stream>>>(
            x, Wt2, prefix, Dn, Bn, C);
        scan_kernel<<<Bn / 4, 256, 0, stream>>>(prefix, Hn, C);
        nade_main<HN, LN><<<(Bn / 8) * C, 512, 0, stream>>>(
            x, Wt2, prefix, bh, aw, ab, llp, Dn, Bn, C);
        final_kernel<<<(Bn + 255) / 256, 256, 0, stream>>>(llp, out, Bn, C);
    } else {
        nade_fallback<<<Bn, 64, 0, stream>>>(x, Wh, bh, aw, ab, out, Dn, Hn);
    }
}

// Round 12
// 114.895 us; speedup vs baseline: 1.1439x; 1.0176x over previous
//
#include <hip/hip_runtime.h>

#define LOG2E  1.44269504088896f
#define NLOG2E (-1.44269504088896f)
#define LN2    0.693147180559945f

// DPP move: returns src value permuted by ctrl (full masks, bound_ctrl=0-fill)
template <int CTRL>
__device__ __forceinline__ float dpp_mov(float x) {
    return __int_as_float(__builtin_amdgcn_update_dpp(
        0, __float_as_int(x), CTRL, 0xF, 0xF, true));
}
// quad_perm: xor1=[1,0,3,2]=0xB1, xor2=[2,3,0,1]=0x4E; row_ror:4=0x124, row_ror:8=0x128

// lane-halves butterfly adds on the VALU pipe (gfx950 permlane*_swap); DS fallback
__device__ __forceinline__ float xor16_add(float x) {
#if __has_builtin(__builtin_amdgcn_permlane16_swap)
    auto sw = __builtin_amdgcn_permlane16_swap(__float_as_int(x), __float_as_int(x),
                                               false, false);
    return __int_as_float(sw[0]) + __int_as_float(sw[1]);
#else
    return x + __shfl_xor(x, 16, 64);
#endif
}
__device__ __forceinline__ float xor32_add(float x) {
#if __has_builtin(__builtin_amdgcn_permlane32_swap)
    auto sw = __builtin_amdgcn_permlane32_swap(__float_as_int(x), __float_as_int(x),
                                               false, false);
    return __int_as_float(sw[0]) + __int_as_float(sw[1]);
#else
    return x + __shfl_xor(x, 32, 64);
#endif
}

// ---------- W_h [H,D] -> W_t [D,H] (pre-scaled by `scale`) ----------
__global__ void transpose_kernel(const float* __restrict__ Wh,
                                 float* __restrict__ Wt, int Hn, int Dn,
                                 float scale) {
    __shared__ float tile[32][33];
    int tx = threadIdx.x;        // 0..31
    int ty = threadIdx.y;        // 0..7
    int i0 = blockIdx.x * 32;    // D tile origin
    int h0 = blockIdx.y * 32;    // H tile origin
#pragma unroll
    for (int k = 0; k < 4; ++k)
        tile[ty + 8 * k][tx] = scale * Wh[(size_t)(h0 + ty + 8 * k) * Dn + (i0 + tx)];
    __syncthreads();
#pragma unroll
    for (int k = 0; k < 4; ++k)
        Wt[(size_t)(i0 + ty + 8 * k) * Hn + (h0 + tx)] = tile[tx][ty + 8 * k];
}

// ---------- pass 1: per-chunk partial x·W sums, 4 batch rows per wave ----------
// Writes RAW per-chunk sums; main sums chunks < c itself (no scan pass).
template <int HN, int LN>
__global__ __launch_bounds__(512) void partial_kernel(
    const float* __restrict__ x, const float* __restrict__ Wt,
    float* __restrict__ partial, int Dn, int Bn, int C)
{
    const int wid  = threadIdx.x >> 6;
    const int lane = threadIdx.x & 63;
    const int gpc  = Bn / 32;        // b-groups (of 32) per c
    const int c    = blockIdx.x / gpc;
    const int b0   = (blockIdx.x % gpc) * 32 + wid * 4;  // 4 b's per wave

    const float* wp  = Wt + (size_t)(c * LN) * HN + lane * 4;
    const float* xp0 = x + (size_t)(b0 + 0) * Dn + c * LN;
    const float* xp1 = x + (size_t)(b0 + 1) * Dn + c * LN;
    const float* xp2 = x + (size_t)(b0 + 2) * Dn + c * LN;
    const float* xp3 = x + (size_t)(b0 + 3) * Dn + c * LN;

    float4 ac0 = make_float4(0.f, 0.f, 0.f, 0.f);
    float4 ac1 = make_float4(0.f, 0.f, 0.f, 0.f);
    float4 ac2 = make_float4(0.f, 0.f, 0.f, 0.f);
    float4 ac3 = make_float4(0.f, 0.f, 0.f, 0.f);

#pragma unroll 2
    for (int ii = 0; ii < LN; ii += 4) {
        const float4 w0 = *(const float4*)(wp);
        const float4 w1 = *(const float4*)(wp + HN);
        const float4 w2 = *(const float4*)(wp + 2 * HN);
        const float4 w3 = *(const float4*)(wp + 3 * HN);
        const float4 xa = *(const float4*)(xp0 + ii);   // wave-uniform
        const float4 xb = *(const float4*)(xp1 + ii);
        const float4 xc = *(const float4*)(xp2 + ii);
        const float4 xd = *(const float4*)(xp3 + ii);
        wp += 4 * HN;

        ac0.x = fmaf(xa.x, w0.x, fmaf(xa.y, w1.x, fmaf(xa.z, w2.x, fmaf(xa.w, w3.x, ac0.x))));
        ac0.y = fmaf(xa.x, w0.y, fmaf(xa.y, w1.y, fmaf(xa.z, w2.y, fmaf(xa.w, w3.y, ac0.y))));
        ac0.z = fmaf(xa.x, w0.z, fmaf(xa.y, w1.z, fmaf(xa.z, w2.z, fmaf(xa.w, w3.z, ac0.z))));
        ac0.w = fmaf(xa.x, w0.w, fmaf(xa.y, w1.w, fmaf(xa.z, w2.w, fmaf(xa.w, w3.w, ac0.w))));

        ac1.x = fmaf(xb.x, w0.x, fmaf(xb.y, w1.x, fmaf(xb.z, w2.x, fmaf(xb.w, w3.x, ac1.x))));
        ac1.y = fmaf(xb.x, w0.y, fmaf(xb.y, w1.y, fmaf(xb.z, w2.y, fmaf(xb.w, w3.y, ac1.y))));
        ac1.z = fmaf(xb.x, w0.z, fmaf(xb.y, w1.z, fmaf(xb.z, w2.z, fmaf(xb.w, w3.z, ac1.z))));
        ac1.w = fmaf(xb.x, w0.w, fmaf(xb.y, w1.w, fmaf(xb.z, w2.w, fmaf(xb.w, w3.w, ac1.w))));

        ac2.x = fmaf(xc.x, w0.x, fmaf(xc.y, w1.x, fmaf(xc.z, w2.x, fmaf(xc.w, w3.x, ac2.x))));
        ac2.y = fmaf(xc.x, w0.y, fmaf(xc.y, w1.y, fmaf(xc.z, w2.y, fmaf(xc.w, w3.y, ac2.y))));
        ac2.z = fmaf(xc.x, w0.z, fmaf(xc.y, w1.z, fmaf(xc.z, w2.z, fmaf(xc.w, w3.z, ac2.z))));
        ac2.w = fmaf(xc.x, w0.w, fmaf(xc.y, w1.w, fmaf(xc.z, w2.w, fmaf(xc.w, w3.w, ac2.w))));

        ac3.x = fmaf(xd.x, w0.x, fmaf(xd.y, w1.x, fmaf(xd.z, w2.x, fmaf(xd.w, w3.x, ac3.x))));
        ac3.y = fmaf(xd.x, w0.y, fmaf(xd.y, w1.y, fmaf(xd.z, w2.y, fmaf(xd.w, w3.y, ac3.y))));
        ac3.z = fmaf(xd.x, w0.z, fmaf(xd.y, w1.z, fmaf(xd.z, w2.z, fmaf(xd.w, w3.z, ac3.z))));
        ac3.w = fmaf(xd.x, w0.w, fmaf(xd.y, w1.w, fmaf(xd.z, w2.w, fmaf(xd.w, w3.w, ac3.w))));
    }

    float* outp = partial + ((size_t)b0 * C + c) * HN + lane * 4;
    *(float4*)(outp)                      = ac0;
    *(float4*)(outp + (size_t)C * HN)     = ac1;
    *(float4*)(outp + (size_t)2 * C * HN) = ac2;
    *(float4*)(outp + (size_t)3 * C * HN) = ac3;
}

// ---------- pass 3: main NADE chunk kernel (8 waves share weight stream) ----
// Scaled domain: Wt2 = -log2e * W^T, partial likewise, bh2 = -log2e * b_h.
// sigma_h = rcp(1 + exp2(u_h));  u += xv*w + bh2 per step.
// Prologue sums raw partial chunks < c (replaces the scan kernel).
template <int HN, int LN>
__global__ __launch_bounds__(512) void nade_main(
    const float* __restrict__ x,      // [B,D]
    const float* __restrict__ Wt2,    // [D,H] transposed, scaled
    const float* __restrict__ partial,// [B,C,H] raw per-chunk sums, scaled
    const float* __restrict__ bh,     // [H] (unscaled)
    const float* __restrict__ aw,     // [D,H]
    const float* __restrict__ ab,     // [D]
    float* __restrict__ llp,          // [B,C] partial log-likelihoods
    int Dn, int Bn, int C)
{
    const int wid  = threadIdx.x >> 6;
    const int lane = threadIdx.x & 63;
    const int bpc  = Bn / 8;
    const int c    = blockIdx.x / bpc;
    const int b    = (blockIdx.x % bpc) * 8 + wid;   // 8 waves: same c, adjacent b
    const int j    = lane & 3;       // this lane's i-class within a 4-batch

    float4 bh2 = *(const float4*)(bh + lane * 4);
    bh2.x *= NLOG2E; bh2.y *= NLOG2E; bh2.z *= NLOG2E; bh2.w *= NLOG2E;

    // exclusive prefix: sum raw partial chunks < c (block-uniform trip count)
    float4 u = make_float4(0.f, 0.f, 0.f, 0.f);
    {
        const float* pp = partial + (size_t)b * C * HN + lane * 4;
        for (int cc = 0; cc < c; ++cc) {
            const float4 pv = *(const float4*)(pp + (size_t)cc * HN);
            u.x += pv.x; u.y += pv.y; u.z += pv.z; u.w += pv.w;
        }
    }
    const float cl = (float)(c * LN);
    u.x = fmaf(cl, bh2.x, u.x); u.y = fmaf(cl, bh2.y, u.y);
    u.z = fmaf(cl, bh2.z, u.z); u.w = fmaf(cl, bh2.w, u.w);

    const int lo = lane * 4;
    const float* awp = aw  + (size_t)(c * LN) * HN + lo;
    const float* wp  = Wt2 + (size_t)(c * LN) * HN + lo;
    const float* xp  = x   + (size_t)b * Dn + c * LN;
    const float* abp = ab  + c * LN;

    float A  = 0.f;                  // sum of lp*(2*x-1) over my i-class
    float Bs = 0.f;                  // sum of x over my i-class

#pragma unroll 4
    for (int ii = 0; ii < LN; ii += 4) {
        // ================= batch load phase (constexpr offsets) =============
        const float4 a0 = *(const float4*)(awp);
        const float4 a1 = *(const float4*)(awp + HN);
        const float4 a2 = *(const float4*)(awp + 2 * HN);
        const float4 a3 = *(const float4*)(awp + 3 * HN);
        const float4 w0 = *(const float4*)(wp);
        const float4 w1 = *(const float4*)(wp + HN);
        const float4 w2 = *(const float4*)(wp + 2 * HN);
        const float4 w3 = *(const float4*)(wp + 3 * HN);
        const float4 x4  = *(const float4*)(xp + ii);    // wave-uniform
        const float4 ab4 = *(const float4*)(abp + ii);   // wave-uniform
        awp += 4 * HN;
        wp  += 4 * HN;

        // per-lane class values via static select (no DS)
        const float t0x = (j & 1) ? x4.y  : x4.x;
        const float t1x = (j & 1) ? x4.w  : x4.z;
        const float xq  = (j & 2) ? t1x   : t0x;
        const float t0a = (j & 1) ? ab4.y : ab4.x;
        const float t1a = (j & 1) ? ab4.w : ab4.z;
        const float abq = (j & 2) ? t1a   : t0a;

        // ================= compute phase ====================================
        float p0, p1, p2, p3;
        {   // m = 0 (sigmoid BEFORE update: exclusive prefix)
            const float s0 = __builtin_amdgcn_rcpf(1.0f + __builtin_amdgcn_exp2f(u.x));
            const float s1 = __builtin_amdgcn_rcpf(1.0f + __builtin_amdgcn_exp2f(u.y));
            const float s2 = __builtin_amdgcn_rcpf(1.0f + __builtin_amdgcn_exp2f(u.z));
            const float s3 = __builtin_amdgcn_rcpf(1.0f + __builtin_amdgcn_exp2f(u.w));
            p0 = fmaf(a0.w, s3, fmaf(a0.z, s2, fmaf(a0.y, s1, a0.x * s0)));
            u.x += fmaf(x4.x, w0.x, bh2.x); u.y += fmaf(x4.x, w0.y, bh2.y);
            u.z += fmaf(x4.x, w0.z, bh2.z); u.w += fmaf(x4.x, w0.w, bh2.w);
        }
        {   // m = 1
            const float s0 = __builtin_amdgcn_rcpf(1.0f + __builtin_amdgcn_exp2f(u.x));
            const float s1 = __builtin_amdgcn_rcpf(1.0f + __builtin_amdgcn_exp2f(u.y));
            const float s2 = __builtin_amdgcn_rcpf(1.0f + __builtin_amdgcn_exp2f(u.z));
            const float s3 = __builtin_amdgcn_rcpf(1.0f + __builtin_amdgcn_exp2f(u.w));
            p1 = fmaf(a1.w, s3, fmaf(a1.z, s2, fmaf(a1.y, s1, a1.x * s0)));
            u.x += fmaf(x4.y, w1.x, bh2.x); u.y += fmaf(x4.y, w1.y, bh2.y);
            u.z += fmaf(x4.y, w1.z, bh2.z); u.w += fmaf(x4.y, w1.w, bh2.w);
        }
        {   // m = 2
            const float s0 = __builtin_amdgcn_rcpf(1.0f + __builtin_amdgcn_exp2f(u.x));
            const float s1 = __builtin_amdgcn_rcpf(1.0f + __builtin_amdgcn_exp2f(u.y));
            const float s2 = __builtin_amdgcn_rcpf(1.0f + __builtin_amdgcn_exp2f(u.z));
            const float s3 = __builtin_amdgcn_rcpf(1.0f + __builtin_amdgcn_exp2f(u.w));
            p2 = fmaf(a2.w, s3, fmaf(a2.z, s2, fmaf(a2.y, s1, a2.x * s0)));
            u.x += fmaf(x4.z, w2.x, bh2.x); u.y += fmaf(x4.z, w2.y, bh2.y);
            u.z += fmaf(x4.z, w2.z, bh2.z); u.w += fmaf(x4.z, w2.w, bh2.w);
        }
        {   // m = 3
            const float s0 = __builtin_amdgcn_rcpf(1.0f + __builtin_amdgcn_exp2f(u.x));
            const float s1 = __builtin_amdgcn_rcpf(1.0f + __builtin_amdgcn_exp2f(u.y));
            const float s2 = __builtin_amdgcn_rcpf(1.0f + __builtin_amdgcn_exp2f(u.z));
            const float s3 = __builtin_amdgcn_rcpf(1.0f + __builtin_amdgcn_exp2f(u.w));
            p3 = fmaf(a3.w, s3, fmaf(a3.z, s2, fmaf(a3.y, s1, a3.x * s0)));
            u.x += fmaf(x4.w, w3.x, bh2.x); u.y += fmaf(x4.w, w3.y, bh2.y);
            u.z += fmaf(x4.w, w3.z, bh2.z); u.w += fmaf(x4.w, w3.w, bh2.w);
        }

        // ======= reduce: DPP quad + select + DPP row + permlane swaps =======
        p0 += dpp_mov<0xB1>(p0); p0 += dpp_mov<0x4E>(p0);
        p1 += dpp_mov<0xB1>(p1); p1 += dpp_mov<0x4E>(p1);
        p2 += dpp_mov<0xB1>(p2); p2 += dpp_mov<0x4E>(p2);
        p3 += dpp_mov<0xB1>(p3); p3 += dpp_mov<0x4E>(p3);
        const float tq0 = (lane & 1) ? p1 : p0;
        const float tq1 = (lane & 1) ? p3 : p2;
        float q = (lane & 2) ? tq1 : tq0;
        q += dpp_mov<0x124>(q);          // row_ror:4  (sum quads in row)
        q += dpp_mov<0x128>(q);          // row_ror:8
        q = xor16_add(q);                // cross-row, VALU pipe
        q = xor32_add(q);
        // q = full 256-h dot for i = c*LN + ii + j (replicated per class)
        const float s = q + abq;
        const float lp = -LN2 *
            __builtin_amdgcn_logf(1.0f + __builtin_amdgcn_exp2f(-s * LOG2E));
        A = fmaf(lp, fmaf(2.0f, xq, -1.0f), A);
        Bs += xq;
    }

    // each class replicated 16x across the wave
#pragma unroll
    for (int off = 32; off > 0; off >>= 1) {
        A  += __shfl_xor(A, off, 64);
        Bs += __shfl_xor(Bs, off, 64);
    }
    if (lane == 0)
        llp[(size_t)b * C + c] = (A - Bs) * (1.0f / 16.0f) + (float)LN;
}

// ---------- pass 4: final reduce ----------
__global__ void final_kernel(const float* __restrict__ llp,
                             float* __restrict__ out, int Bn, int C) {
    const int b = blockIdx.x * blockDim.x + threadIdx.x;
    if (b < Bn) {
        float s = 0.f;
        for (int c = 0; c < C; ++c) s += llp[(size_t)b * C + c];
        out[b] = s;
    }
}

// ---------- fallback (round-1 style, unscaled) ----------
__global__ __launch_bounds__(64) void nade_fallback(
    const float* __restrict__ x, const float* __restrict__ Wh,
    const float* __restrict__ bh, const float* __restrict__ aw,
    const float* __restrict__ ab, float* __restrict__ out, int Dn, int Hn)
{
    const int b    = blockIdx.x;
    const int lane = threadIdx.x;
    const float* xrow = x + (size_t)b * Dn;
    float ll = 0.f;
    float accl[8];
    float bhl[8];
    for (int k = 0; k < 8; ++k) { accl[k] = 0.f; bhl[k] = 0.f; }
    const int hper = Hn / 64;
    for (int k = 0; k < hper && k < 8; ++k) bhl[k] = bh[lane * hper + k];
    for (int i = 0; i < Dn; ++i) {
        float pm = 0.f;
        for (int k = 0; k < hper && k < 8; ++k) {
            const int h = lane * hper + k;
            const float sg = __builtin_amdgcn_rcpf(
                1.0f + __builtin_amdgcn_exp2f(-accl[k] * LOG2E));
            pm = fmaf(aw[(size_t)i * Hn + h], sg, pm);
        }
        for (int off = 32; off > 0; off >>= 1) pm += __shfl_xor(pm, off, 64);
        const float s = pm + ab[i];
        const float lp = -LN2 *
            __builtin_amdgcn_logf(1.0f + __builtin_amdgcn_exp2f(-s * LOG2E));
        const float xv = xrow[i];
        ll += xv * lp + (1.0f - xv) * (1.0f - lp);
        for (int k = 0; k < hper && k < 8; ++k) {
            const int h = lane * hper + k;
            accl[k] = fmaf(xv, Wh[(size_t)h * Dn + i], accl[k]) + bhl[k];
        }
    }
    if (lane == 0) out[b] = ll;
}

extern "C" void kernel_launch(void* const* d_in, const int* in_sizes, int n_in,
                              void* d_out, int out_size, void* d_ws, size_t ws_size,
                              hipStream_t stream) {
    const float* x  = (const float*)d_in[0];
    const float* Wh = (const float*)d_in[1];
    const float* bh = (const float*)d_in[2];
    const float* aw = (const float*)d_in[3];
    const float* ab = (const float*)d_in[4];
    float* out = (float*)d_out;

    const int Bn = out_size;          // 1024
    const int Hn = in_sizes[2];       // 256
    const int Dn = in_sizes[4];       // 1024
    constexpr int HN = 256;
    constexpr int LN = 128;
    const int C = 8;

    const size_t wt_bytes  = (size_t)Dn * Hn * sizeof(float);
    const size_t pf_bytes  = (size_t)Bn * C * Hn * sizeof(float);
    const size_t llp_bytes = (size_t)Bn * C * sizeof(float);

    const bool shapes_ok = (Hn == HN) && (Dn == C * LN) && (Bn % 32 == 0);
    const bool full_path = shapes_ok && ws_size >= wt_bytes + pf_bytes + llp_bytes;

    if (full_path) {
        float* Wt2     = (float*)d_ws;
        float* partial = (float*)((char*)d_ws + wt_bytes);
        float* llp     = (float*)((char*)d_ws + wt_bytes + pf_bytes);

        transpose_kernel<<<dim3(Dn / 32, Hn / 32), dim3(32, 8), 0, stream>>>(
            Wh, Wt2, Hn, Dn, NLOG2E);
        partial_kernel<HN, LN><<<(Bn / 32) * C, 512, 0, stream>>>(
            x, Wt2, partial, Dn, Bn, C);
        nade_main<HN, LN><<<(Bn / 8) * C, 512, 0, stream>>>(
            x, Wt2, partial, bh, aw, ab, llp, Dn, Bn, C);
        final_kernel<<<(Bn + 255) / 256, 256, 0, stream>>>(llp, out, Bn, C);
    } else {
        nade_fallback<<<Bn, 64, 0, stream>>>(x, Wh, bh, aw, ab, out, Dn, Hn);
    }
}

// Round 13
// 114.516 us; speedup vs baseline: 1.1476x; 1.0033x over previous
//
#include <hip/hip_runtime.h>

#define LOG2E  1.44269504088896f
#define NLOG2E (-1.44269504088896f)
#define LN2    0.693147180559945f

typedef __attribute__((ext_vector_type(2))) float f32x2;

// DPP move: returns src value permuted by ctrl (full masks, bound_ctrl=0-fill)
template <int CTRL>
__device__ __forceinline__ float dpp_mov(float x) {
    return __int_as_float(__builtin_amdgcn_update_dpp(
        0, __float_as_int(x), CTRL, 0xF, 0xF, true));
}
// quad_perm: xor1=[1,0,3,2]=0xB1, xor2=[2,3,0,1]=0x4E; row_ror:4=0x124, row_ror:8=0x128

// lane-halves butterfly adds on the VALU pipe (gfx950 permlane*_swap); DS fallback
__device__ __forceinline__ float xor16_add(float x) {
#if __has_builtin(__builtin_amdgcn_permlane16_swap)
    auto sw = __builtin_amdgcn_permlane16_swap(__float_as_int(x), __float_as_int(x),
                                               false, false);
    return __int_as_float(sw[0]) + __int_as_float(sw[1]);
#else
    return x + __shfl_xor(x, 16, 64);
#endif
}
__device__ __forceinline__ float xor32_add(float x) {
#if __has_builtin(__builtin_amdgcn_permlane32_swap)
    auto sw = __builtin_amdgcn_permlane32_swap(__float_as_int(x), __float_as_int(x),
                                               false, false);
    return __int_as_float(sw[0]) + __int_as_float(sw[1]);
#else
    return x + __shfl_xor(x, 32, 64);
#endif
}

// ---------- W_h [H,D] -> W_t [D,H] (pre-scaled by `scale`) ----------
__global__ void transpose_kernel(const float* __restrict__ Wh,
                                 float* __restrict__ Wt, int Hn, int Dn,
                                 float scale) {
    __shared__ float tile[32][33];
    int tx = threadIdx.x;        // 0..31
    int ty = threadIdx.y;        // 0..7
    int i0 = blockIdx.x * 32;    // D tile origin
    int h0 = blockIdx.y * 32;    // H tile origin
#pragma unroll
    for (int k = 0; k < 4; ++k)
        tile[ty + 8 * k][tx] = scale * Wh[(size_t)(h0 + ty + 8 * k) * Dn + (i0 + tx)];
    __syncthreads();
#pragma unroll
    for (int k = 0; k < 4; ++k)
        Wt[(size_t)(i0 + ty + 8 * k) * Hn + (h0 + tx)] = tile[tx][ty + 8 * k];
}

// ---------- pass 1: per-chunk partial x·W sums, 4 batch rows per wave ----------
// Writes RAW per-chunk sums; main sums chunks < c itself (no scan pass).
template <int HN, int LN>
__global__ __launch_bounds__(512) void partial_kernel(
    const float* __restrict__ x, const float* __restrict__ Wt,
    float* __restrict__ partial, int Dn, int Bn, int C)
{
    const int wid  = threadIdx.x >> 6;
    const int lane = threadIdx.x & 63;
    const int gpc  = Bn / 32;        // b-groups (of 32) per c
    const int c    = blockIdx.x / gpc;
    const int b0   = (blockIdx.x % gpc) * 32 + wid * 4;  // 4 b's per wave

    const float* wp  = Wt + (size_t)(c * LN) * HN + lane * 4;
    const float* xp0 = x + (size_t)(b0 + 0) * Dn + c * LN;
    const float* xp1 = x + (size_t)(b0 + 1) * Dn + c * LN;
    const float* xp2 = x + (size_t)(b0 + 2) * Dn + c * LN;
    const float* xp3 = x + (size_t)(b0 + 3) * Dn + c * LN;

    float4 ac0 = make_float4(0.f, 0.f, 0.f, 0.f);
    float4 ac1 = make_float4(0.f, 0.f, 0.f, 0.f);
    float4 ac2 = make_float4(0.f, 0.f, 0.f, 0.f);
    float4 ac3 = make_float4(0.f, 0.f, 0.f, 0.f);

#pragma unroll 2
    for (int ii = 0; ii < LN; ii += 4) {
        const float4 w0 = *(const float4*)(wp);
        const float4 w1 = *(const float4*)(wp + HN);
        const float4 w2 = *(const float4*)(wp + 2 * HN);
        const float4 w3 = *(const float4*)(wp + 3 * HN);
        const float4 xa = *(const float4*)(xp0 + ii);   // wave-uniform
        const float4 xb = *(const float4*)(xp1 + ii);
        const float4 xc = *(const float4*)(xp2 + ii);
        const float4 xd = *(const float4*)(xp3 + ii);
        wp += 4 * HN;

        ac0.x = fmaf(xa.x, w0.x, fmaf(xa.y, w1.x, fmaf(xa.z, w2.x, fmaf(xa.w, w3.x, ac0.x))));
        ac0.y = fmaf(xa.x, w0.y, fmaf(xa.y, w1.y, fmaf(xa.z, w2.y, fmaf(xa.w, w3.y, ac0.y))));
        ac0.z = fmaf(xa.x, w0.z, fmaf(xa.y, w1.z, fmaf(xa.z, w2.z, fmaf(xa.w, w3.z, ac0.z))));
        ac0.w = fmaf(xa.x, w0.w, fmaf(xa.y, w1.w, fmaf(xa.z, w2.w, fmaf(xa.w, w3.w, ac0.w))));

        ac1.x = fmaf(xb.x, w0.x, fmaf(xb.y, w1.x, fmaf(xb.z, w2.x, fmaf(xb.w, w3.x, ac1.x))));
        ac1.y = fmaf(xb.x, w0.y, fmaf(xb.y, w1.y, fmaf(xb.z, w2.y, fmaf(xb.w, w3.y, ac1.y))));
        ac1.z = fmaf(xb.x, w0.z, fmaf(xb.y, w1.z, fmaf(xb.z, w2.z, fmaf(xb.w, w3.z, ac1.z))));
        ac1.w = fmaf(xb.x, w0.w, fmaf(xb.y, w1.w, fmaf(xb.z, w2.w, fmaf(xb.w, w3.w, ac1.w))));

        ac2.x = fmaf(xc.x, w0.x, fmaf(xc.y, w1.x, fmaf(xc.z, w2.x, fmaf(xc.w, w3.x, ac2.x))));
        ac2.y = fmaf(xc.x, w0.y, fmaf(xc.y, w1.y, fmaf(xc.z, w2.y, fmaf(xc.w, w3.y, ac2.y))));
        ac2.z = fmaf(xc.x, w0.z, fmaf(xc.y, w1.z, fmaf(xc.z, w2.z, fmaf(xc.w, w3.z, ac2.z))));
        ac2.w = fmaf(xc.x, w0.w, fmaf(xc.y, w1.w, fmaf(xc.z, w2.w, fmaf(xc.w, w3.w, ac2.w))));

        ac3.x = fmaf(xd.x, w0.x, fmaf(xd.y, w1.x, fmaf(xd.z, w2.x, fmaf(xd.w, w3.x, ac3.x))));
        ac3.y = fmaf(xd.x, w0.y, fmaf(xd.y, w1.y, fmaf(xd.z, w2.y, fmaf(xd.w, w3.y, ac3.y))));
        ac3.z = fmaf(xd.x, w0.z, fmaf(xd.y, w1.z, fmaf(xd.z, w2.z, fmaf(xd.w, w3.z, ac3.z))));
        ac3.w = fmaf(xd.x, w0.w, fmaf(xd.y, w1.w, fmaf(xd.z, w2.w, fmaf(xd.w, w3.w, ac3.w))));
    }

    float* outp = partial + ((size_t)b0 * C + c) * HN + lane * 4;
    *(float4*)(outp)                      = ac0;
    *(float4*)(outp + (size_t)C * HN)     = ac1;
    *(float4*)(outp + (size_t)2 * C * HN) = ac2;
    *(float4*)(outp + (size_t)3 * C * HN) = ac3;
}

// ---------- pass 3: main NADE chunk kernel (8 waves share weight stream) ----
// Scaled domain: Wt2 = -log2e * W^T, partial likewise, bh2 = -log2e * b_h.
// sigma_h = rcp(1 + exp2(u_h));  u += xv*w + bh2 per step.
// f32x2-packed FMA chains -> v_pk_fma_f32 / v_pk_add_f32 (full-rate 2x f32).
template <int HN, int LN>
__global__ __launch_bounds__(512) void nade_main(
    const float* __restrict__ x,      // [B,D]
    const float* __restrict__ Wt2,    // [D,H] transposed, scaled
    const float* __restrict__ partial,// [B,C,H] raw per-chunk sums, scaled
    const float* __restrict__ bh,     // [H] (unscaled)
    const float* __restrict__ aw,     // [D,H]
    const float* __restrict__ ab,     // [D]
    float* __restrict__ llp,          // [B,C] partial log-likelihoods
    int Dn, int Bn, int C)
{
    const int wid  = threadIdx.x >> 6;
    const int lane = threadIdx.x & 63;
    const int bpc  = Bn / 8;
    const int c    = blockIdx.x / bpc;
    const int b    = (blockIdx.x % bpc) * 8 + wid;   // 8 waves: same c, adjacent b
    const int j    = lane & 3;       // this lane's i-class within a 4-batch

    const f32x2* bhp = (const f32x2*)(bh + lane * 4);
    f32x2 bh01 = bhp[0] * NLOG2E;
    f32x2 bh23 = bhp[1] * NLOG2E;

    // exclusive prefix: sum raw partial chunks < c (block-uniform trip count)
    f32x2 u01 = {0.f, 0.f}, u23 = {0.f, 0.f};
    {
        const float* pp = partial + (size_t)b * C * HN + lane * 4;
        for (int cc = 0; cc < c; ++cc) {
            const float4 pv = *(const float4*)(pp + (size_t)cc * HN);
            u01.x += pv.x; u01.y += pv.y; u23.x += pv.z; u23.y += pv.w;
        }
    }
    const float cl = (float)(c * LN);
    u01 = __builtin_elementwise_fma((f32x2){cl, cl}, bh01, u01);
    u23 = __builtin_elementwise_fma((f32x2){cl, cl}, bh23, u23);

    const int lo = lane * 4;
    const float* awp = aw  + (size_t)(c * LN) * HN + lo;
    const float* wp  = Wt2 + (size_t)(c * LN) * HN + lo;
    const float* xp  = x   + (size_t)b * Dn + c * LN;
    const float* abp = ab  + c * LN;

    float A  = 0.f;                  // sum of lp*(2*x-1) over my i-class
    float Bs = 0.f;                  // sum of x over my i-class

#pragma unroll 2
    for (int ii = 0; ii < LN; ii += 4) {
        // ================= batch load phase (constexpr offsets) =============
        const float4 a0 = *(const float4*)(awp);
        const float4 a1 = *(const float4*)(awp + HN);
        const float4 a2 = *(const float4*)(awp + 2 * HN);
        const float4 a3 = *(const float4*)(awp + 3 * HN);
        const float4 w0 = *(const float4*)(wp);
        const float4 w1 = *(const float4*)(wp + HN);
        const float4 w2 = *(const float4*)(wp + 2 * HN);
        const float4 w3 = *(const float4*)(wp + 3 * HN);
        const float4 x4  = *(const float4*)(xp + ii);    // wave-uniform
        const float4 ab4 = *(const float4*)(abp + ii);   // wave-uniform
        awp += 4 * HN;
        wp  += 4 * HN;

        // per-lane class values via static select (no DS)
        const float t0x = (j & 1) ? x4.y  : x4.x;
        const float t1x = (j & 1) ? x4.w  : x4.z;
        const float xq  = (j & 2) ? t1x   : t0x;
        const float t0a = (j & 1) ? ab4.y : ab4.x;
        const float t1a = (j & 1) ? ab4.w : ab4.z;
        const float abq = (j & 2) ? t1a   : t0a;

        // ================= compute phase (f32x2-packed) =====================
        float p0, p1, p2, p3;
#define NADE_STEP(POUT, AV, WV, XS)                                            \
        {                                                                      \
            const f32x2 d01 = { 1.0f + __builtin_amdgcn_exp2f(u01.x),          \
                                1.0f + __builtin_amdgcn_exp2f(u01.y) };        \
            const f32x2 d23 = { 1.0f + __builtin_amdgcn_exp2f(u23.x),          \
                                1.0f + __builtin_amdgcn_exp2f(u23.y) };        \
            const f32x2 s01 = { __builtin_amdgcn_rcpf(d01.x),                  \
                                __builtin_amdgcn_rcpf(d01.y) };                \
            const f32x2 s23 = { __builtin_amdgcn_rcpf(d23.x),                  \
                                __builtin_amdgcn_rcpf(d23.y) };                \
            const f32x2 pa = __builtin_elementwise_fma(                        \
                (f32x2){AV.z, AV.w}, s23, (f32x2){AV.x, AV.y} * s01);          \
            POUT = pa.x + pa.y;                                                \
            const f32x2 xv2 = {XS, XS};                                        \
            u01 += __builtin_elementwise_fma(xv2, (f32x2){WV.x, WV.y}, bh01);  \
            u23 += __builtin_elementwise_fma(xv2, (f32x2){WV.z, WV.w}, bh23);  \
        }
        NADE_STEP(p0, a0, w0, x4.x)   // sigmoid BEFORE update: exclusive prefix
        NADE_STEP(p1, a1, w1, x4.y)
        NADE_STEP(p2, a2, w2, x4.z)
        NADE_STEP(p3, a3, w3, x4.w)
#undef NADE_STEP

        // ======= reduce: DPP quad + select + DPP row + permlane swaps =======
        p0 += dpp_mov<0xB1>(p0); p0 += dpp_mov<0x4E>(p0);
        p1 += dpp_mov<0xB1>(p1); p1 += dpp_mov<0x4E>(p1);
        p2 += dpp_mov<0xB1>(p2); p2 += dpp_mov<0x4E>(p2);
        p3 += dpp_mov<0xB1>(p3); p3 += dpp_mov<0x4E>(p3);
        const float tq0 = (lane & 1) ? p1 : p0;
        const float tq1 = (lane & 1) ? p3 : p2;
        float q = (lane & 2) ? tq1 : tq0;
        q += dpp_mov<0x124>(q);          // row_ror:4  (sum quads in row)
        q += dpp_mov<0x128>(q);          // row_ror:8
        q = xor16_add(q);                // cross-row, VALU pipe
        q = xor32_add(q);
        // q = full 256-h dot for i = c*LN + ii + j (replicated per class)
        const float s = q + abq;
        const float lp = -LN2 *
            __builtin_amdgcn_logf(1.0f + __builtin_amdgcn_exp2f(-s * LOG2E));
        A = fmaf(lp, fmaf(2.0f, xq, -1.0f), A);
        Bs += xq;
    }

    // each class replicated 16x across the wave
#pragma unroll
    for (int off = 32; off > 0; off >>= 1) {
        A  += __shfl_xor(A, off, 64);
        Bs += __shfl_xor(Bs, off, 64);
    }
    if (lane == 0)
        llp[(size_t)b * C + c] = (A - Bs) * (1.0f / 16.0f) + (float)LN;
}

// ---------- pass 4: final reduce ----------
__global__ void final_kernel(const float* __restrict__ llp,
                             float* __restrict__ out, int Bn, int C) {
    const int b = blockIdx.x * blockDim.x + threadIdx.x;
    if (b < Bn) {
        float s = 0.f;
        for (int c = 0; c < C; ++c) s += llp[(size_t)b * C + c];
        out[b] = s;
    }
}

// ---------- fallback (round-1 style, unscaled) ----------
__global__ __launch_bounds__(64) void nade_fallback(
    const float* __restrict__ x, const float* __restrict__ Wh,
    const float* __restrict__ bh, const float* __restrict__ aw,
    const float* __restrict__ ab, float* __restrict__ out, int Dn, int Hn)
{
    const int b    = blockIdx.x;
    const int lane = threadIdx.x;
    const float* xrow = x + (size_t)b * Dn;
    float ll = 0.f;
    float accl[8];
    float bhl[8];
    for (int k = 0; k < 8; ++k) { accl[k] = 0.f; bhl[k] = 0.f; }
    const int hper = Hn / 64;
    for (int k = 0; k < hper && k < 8; ++k) bhl[k] = bh[lane * hper + k];
    for (int i = 0; i < Dn; ++i) {
        float pm = 0.f;
        for (int k = 0; k < hper && k < 8; ++k) {
            const int h = lane * hper + k;
            const float sg = __builtin_amdgcn_rcpf(
                1.0f + __builtin_amdgcn_exp2f(-accl[k] * LOG2E));
            pm = fmaf(aw[(size_t)i * Hn + h], sg, pm);
        }
        for (int off = 32; off > 0; off >>= 1) pm += __shfl_xor(pm, off, 64);
        const float s = pm + ab[i];
        const float lp = -LN2 *
            __builtin_amdgcn_logf(1.0f + __builtin_amdgcn_exp2f(-s * LOG2E));
        const float xv = xrow[i];
        ll += xv * lp + (1.0f - xv) * (1.0f - lp);
        for (int k = 0; k < hper && k < 8; ++k) {
            const int h = lane * hper + k;
            accl[k] = fmaf(xv, Wh[(size_t)h * Dn + i], accl[k]) + bhl[k];
        }
    }
    if (lane == 0) out[b] = ll;
}

extern "C" void kernel_launch(void* const* d_in, const int* in_sizes, int n_in,
                              void* d_out, int out_size, void* d_ws, size_t ws_size,
                              hipStream_t stream) {
    const float* x  = (const float*)d_in[0];
    const float* Wh = (const float*)d_in[1];
    const float* bh = (const float*)d_in[2];
    const float* aw = (const float*)d_in[3];
    const float* ab = (const float*)d_in[4];
    float* out = (float*)d_out;

    const int Bn = out_size;          // 1024
    const int Hn = in_sizes[2];       // 256
    const int Dn = in_sizes[4];       // 1024
    constexpr int HN = 256;
    constexpr int LN = 128;
    const int C = 8;

    const size_t wt_bytes  = (size_t)Dn * Hn * sizeof(float);
    const size_t pf_bytes  = (size_t)Bn * C * Hn * sizeof(float);
    const size_t llp_bytes = (size_t)Bn * C * sizeof(float);

    const bool shapes_ok = (Hn == HN) && (Dn == C * LN) && (Bn % 32 == 0);
    const bool full_path = shapes_ok && ws_size >= wt_bytes + pf_bytes + llp_bytes;

    if (full_path) {
        float* Wt2     = (float*)d_ws;
        float* partial = (float*)((char*)d_ws + wt_bytes);
        float* llp     = (float*)((char*)d_ws + wt_bytes + pf_bytes);

        transpose_kernel<<<dim3(Dn / 32, Hn / 32), dim3(32, 8), 0, stream>>>(
            Wh, Wt2, Hn, Dn, NLOG2E);
        partial_kernel<HN, LN><<<(Bn / 32) * C, 512, 0, stream>>>(
            x, Wt2, partial, Dn, Bn, C);
        nade_main<HN, LN><<<(Bn / 8) * C, 512, 0, stream>>>(
            x, Wt2, partial, bh, aw, ab, llp, Dn, Bn, C);
        final_kernel<<<(Bn + 255) / 256, 256, 0, stream>>>(llp, out, Bn, C);
    } else {
        nade_fallback<<<Bn, 64, 0, stream>>>(x, Wh, bh, aw, ab, out, Dn, Hn);
    }
}

// Round 14
// 110.018 us; speedup vs baseline: 1.1946x; 1.0409x over previous
//
#include <hip/hip_runtime.h>

#define LOG2E  1.44269504088896f
#define NLOG2E (-1.44269504088896f)
#define LN2    0.693147180559945f

// DPP move: returns src value permuted by ctrl (full masks, bound_ctrl=0-fill)
template <int CTRL>
__device__ __forceinline__ float dpp_mov(float x) {
    return __int_as_float(__builtin_amdgcn_update_dpp(
        0, __float_as_int(x), CTRL, 0xF, 0xF, true));
}
// quad_perm: xor1=[1,0,3,2]=0xB1, xor2=[2,3,0,1]=0x4E; row_ror:4=0x124, row_ror:8=0x128

// lane-halves butterfly adds on the VALU pipe (gfx950 permlane*_swap); DS fallback
__device__ __forceinline__ float xor16_add(float x) {
#if __has_builtin(__builtin_amdgcn_permlane16_swap)
    auto sw = __builtin_amdgcn_permlane16_swap(__float_as_int(x), __float_as_int(x),
                                               false, false);
    return __int_as_float(sw[0]) + __int_as_float(sw[1]);
#else
    return x + __shfl_xor(x, 16, 64);
#endif
}
__device__ __forceinline__ float xor32_add(float x) {
#if __has_builtin(__builtin_amdgcn_permlane32_swap)
    auto sw = __builtin_amdgcn_permlane32_swap(__float_as_int(x), __float_as_int(x),
                                               false, false);
    return __int_as_float(sw[0]) + __int_as_float(sw[1]);
#else
    return x + __shfl_xor(x, 32, 64);
#endif
}

// ---------- W_h [H,D] -> W_t [D,H] (pre-scaled by `scale`) ----------
__global__ void transpose_kernel(const float* __restrict__ Wh,
                                 float* __restrict__ Wt, int Hn, int Dn,
                                 float scale) {
    __shared__ float tile[32][33];
    int tx = threadIdx.x;        // 0..31
    int ty = threadIdx.y;        // 0..7
    int i0 = blockIdx.x * 32;    // D tile origin
    int h0 = blockIdx.y * 32;    // H tile origin
#pragma unroll
    for (int k = 0; k < 4; ++k)
        tile[ty + 8 * k][tx] = scale * Wh[(size_t)(h0 + ty + 8 * k) * Dn + (i0 + tx)];
    __syncthreads();
#pragma unroll
    for (int k = 0; k < 4; ++k)
        Wt[(size_t)(i0 + ty + 8 * k) * Hn + (h0 + tx)] = tile[tx][ty + 8 * k];
}

// ---------- pass 1: per-chunk partial x·W sums, 4 batch rows per wave ----------
// Writes RAW per-chunk sums; main sums chunks < c itself (no scan pass).
template <int HN, int LN>
__global__ __launch_bounds__(512) void partial_kernel(
    const float* __restrict__ x, const float* __restrict__ Wt,
    float* __restrict__ partial, int Dn, int Bn, int C)
{
    const int wid  = threadIdx.x >> 6;
    const int lane = threadIdx.x & 63;
    const int gpc  = Bn / 32;        // b-groups (of 32) per c
    const int c    = blockIdx.x / gpc;
    const int b0   = (blockIdx.x % gpc) * 32 + wid * 4;  // 4 b's per wave

    const float* wp  = Wt + (size_t)(c * LN) * HN + lane * 4;
    const float* xp0 = x + (size_t)(b0 + 0) * Dn + c * LN;
    const float* xp1 = x + (size_t)(b0 + 1) * Dn + c * LN;
    const float* xp2 = x + (size_t)(b0 + 2) * Dn + c * LN;
    const float* xp3 = x + (size_t)(b0 + 3) * Dn + c * LN;

    float4 ac0 = make_float4(0.f, 0.f, 0.f, 0.f);
    float4 ac1 = make_float4(0.f, 0.f, 0.f, 0.f);
    float4 ac2 = make_float4(0.f, 0.f, 0.f, 0.f);
    float4 ac3 = make_float4(0.f, 0.f, 0.f, 0.f);

#pragma unroll 2
    for (int ii = 0; ii < LN; ii += 4) {
        const float4 w0 = *(const float4*)(wp);
        const float4 w1 = *(const float4*)(wp + HN);
        const float4 w2 = *(const float4*)(wp + 2 * HN);
        const float4 w3 = *(const float4*)(wp + 3 * HN);
        const float4 xa = *(const float4*)(xp0 + ii);   // wave-uniform
        const float4 xb = *(const float4*)(xp1 + ii);
        const float4 xc = *(const float4*)(xp2 + ii);
        const float4 xd = *(const float4*)(xp3 + ii);
        wp += 4 * HN;

        ac0.x = fmaf(xa.x, w0.x, fmaf(xa.y, w1.x, fmaf(xa.z, w2.x, fmaf(xa.w, w3.x, ac0.x))));
        ac0.y = fmaf(xa.x, w0.y, fmaf(xa.y, w1.y, fmaf(xa.z, w2.y, fmaf(xa.w, w3.y, ac0.y))));
        ac0.z = fmaf(xa.x, w0.z, fmaf(xa.y, w1.z, fmaf(xa.z, w2.z, fmaf(xa.w, w3.z, ac0.z))));
        ac0.w = fmaf(xa.x, w0.w, fmaf(xa.y, w1.w, fmaf(xa.z, w2.w, fmaf(xa.w, w3.w, ac0.w))));

        ac1.x = fmaf(xb.x, w0.x, fmaf(xb.y, w1.x, fmaf(xb.z, w2.x, fmaf(xb.w, w3.x, ac1.x))));
        ac1.y = fmaf(xb.x, w0.y, fmaf(xb.y, w1.y, fmaf(xb.z, w2.y, fmaf(xb.w, w3.y, ac1.y))));
        ac1.z = fmaf(xb.x, w0.z, fmaf(xb.y, w1.z, fmaf(xb.z, w2.z, fmaf(xb.w, w3.z, ac1.z))));
        ac1.w = fmaf(xb.x, w0.w, fmaf(xb.y, w1.w, fmaf(xb.z, w2.w, fmaf(xb.w, w3.w, ac1.w))));

        ac2.x = fmaf(xc.x, w0.x, fmaf(xc.y, w1.x, fmaf(xc.z, w2.x, fmaf(xc.w, w3.x, ac2.x))));
        ac2.y = fmaf(xc.x, w0.y, fmaf(xc.y, w1.y, fmaf(xc.z, w2.y, fmaf(xc.w, w3.y, ac2.y))));
        ac2.z = fmaf(xc.x, w0.z, fmaf(xc.y, w1.z, fmaf(xc.z, w2.z, fmaf(xc.w, w3.z, ac2.z))));
        ac2.w = fmaf(xc.x, w0.w, fmaf(xc.y, w1.w, fmaf(xc.z, w2.w, fmaf(xc.w, w3.w, ac2.w))));

        ac3.x = fmaf(xd.x, w0.x, fmaf(xd.y, w1.x, fmaf(xd.z, w2.x, fmaf(xd.w, w3.x, ac3.x))));
        ac3.y = fmaf(xd.x, w0.y, fmaf(xd.y, w1.y, fmaf(xd.z, w2.y, fmaf(xd.w, w3.y, ac3.y))));
        ac3.z = fmaf(xd.x, w0.z, fmaf(xd.y, w1.z, fmaf(xd.z, w2.z, fmaf(xd.w, w3.z, ac3.z))));
        ac3.w = fmaf(xd.x, w0.w, fmaf(xd.y, w1.w, fmaf(xd.z, w2.w, fmaf(xd.w, w3.w, ac3.w))));
    }

    float* outp = partial + ((size_t)b0 * C + c) * HN + lane * 4;
    *(float4*)(outp)                      = ac0;
    *(float4*)(outp + (size_t)C * HN)     = ac1;
    *(float4*)(outp + (size_t)2 * C * HN) = ac2;
    *(float4*)(outp + (size_t)3 * C * HN) = ac3;
}

// ---------- pass 3: main NADE chunk kernel (2 batch rows per wave) ----------
// Scaled domain: Wt2 = -log2e * W^T, partial likewise, bh2 = -log2e * b_h.
// sigma_h = rcp(1 + exp2(u_h));  u += xv*w + bh2 per step.
// Each wave runs TWO batch rows (b0, b0+1) against ONE weight-load stream:
// halves L1 port traffic per unit work (the co-limiting resource at R13),
// and doubles per-wave ILP so 4 waves/SIMD still cover load latency.
template <int HN, int LN>
__global__ __launch_bounds__(512) void nade_main(
    const float* __restrict__ x,      // [B,D]
    const float* __restrict__ Wt2,    // [D,H] transposed, scaled
    const float* __restrict__ partial,// [B,C,H] raw per-chunk sums, scaled
    const float* __restrict__ bh,     // [H] (unscaled)
    const float* __restrict__ aw,     // [D,H]
    const float* __restrict__ ab,     // [D]
    float* __restrict__ llp,          // [B,C] partial log-likelihoods
    int Dn, int Bn, int C)
{
    const int wid  = threadIdx.x >> 6;
    const int lane = threadIdx.x & 63;
    const int gpc  = Bn / 16;        // b-pair-groups per c
    const int c    = blockIdx.x / gpc;
    const int b0   = (blockIdx.x % gpc) * 16 + wid * 2;  // waves share c; 2 b's each
    const int b1   = b0 + 1;
    const int j    = lane & 3;       // this lane's i-class within a 4-batch

    float4 bh2 = *(const float4*)(bh + lane * 4);
    bh2.x *= NLOG2E; bh2.y *= NLOG2E; bh2.z *= NLOG2E; bh2.w *= NLOG2E;

    // exclusive prefix: sum raw partial chunks < c (block-uniform trip count)
    float4 ua = make_float4(0.f, 0.f, 0.f, 0.f);
    float4 ub = make_float4(0.f, 0.f, 0.f, 0.f);
    {
        const float* pa = partial + (size_t)b0 * C * HN + lane * 4;
        const float* pb = partial + (size_t)b1 * C * HN + lane * 4;
        for (int cc = 0; cc < c; ++cc) {
            const float4 va = *(const float4*)(pa + (size_t)cc * HN);
            const float4 vb = *(const float4*)(pb + (size_t)cc * HN);
            ua.x += va.x; ua.y += va.y; ua.z += va.z; ua.w += va.w;
            ub.x += vb.x; ub.y += vb.y; ub.z += vb.z; ub.w += vb.w;
        }
    }
    const float cl = (float)(c * LN);
    ua.x = fmaf(cl, bh2.x, ua.x); ua.y = fmaf(cl, bh2.y, ua.y);
    ua.z = fmaf(cl, bh2.z, ua.z); ua.w = fmaf(cl, bh2.w, ua.w);
    ub.x = fmaf(cl, bh2.x, ub.x); ub.y = fmaf(cl, bh2.y, ub.y);
    ub.z = fmaf(cl, bh2.z, ub.z); ub.w = fmaf(cl, bh2.w, ub.w);

    const int lo = lane * 4;
    const float* awp = aw  + (size_t)(c * LN) * HN + lo;
    const float* wp  = Wt2 + (size_t)(c * LN) * HN + lo;
    const float* xpa = x   + (size_t)b0 * Dn + c * LN;
    const float* xpb = x   + (size_t)b1 * Dn + c * LN;
    const float* abp = ab  + c * LN;

    float Aa = 0.f, Ba = 0.f;        // row b0 accumulators
    float Ab = 0.f, Bb = 0.f;        // row b1

#pragma unroll 2
    for (int ii = 0; ii < LN; ii += 4) {
        // ========== batch load phase (weights SHARED between b0,b1) =========
        const float4 a0 = *(const float4*)(awp);
        const float4 a1 = *(const float4*)(awp + HN);
        const float4 a2 = *(const float4*)(awp + 2 * HN);
        const float4 a3 = *(const float4*)(awp + 3 * HN);
        const float4 w0 = *(const float4*)(wp);
        const float4 w1 = *(const float4*)(wp + HN);
        const float4 w2 = *(const float4*)(wp + 2 * HN);
        const float4 w3 = *(const float4*)(wp + 3 * HN);
        const float4 x4a = *(const float4*)(xpa + ii);   // wave-uniform
        const float4 x4b = *(const float4*)(xpb + ii);   // wave-uniform
        const float4 ab4 = *(const float4*)(abp + ii);   // wave-uniform
        awp += 4 * HN;
        wp  += 4 * HN;

        // per-lane class values via static select (no DS)
        const float t0a = (j & 1) ? x4a.y : x4a.x;
        const float t1a = (j & 1) ? x4a.w : x4a.z;
        const float xqa = (j & 2) ? t1a  : t0a;
        const float t0b = (j & 1) ? x4b.y : x4b.x;
        const float t1b = (j & 1) ? x4b.w : x4b.z;
        const float xqb = (j & 2) ? t1b  : t0b;
        const float t0c = (j & 1) ? ab4.y : ab4.x;
        const float t1c = (j & 1) ? ab4.w : ab4.z;
        const float abq = (j & 2) ? t1c  : t0c;

        // ========== compute phase: 4 steps x 2 b-instances ==================
        float pa0, pa1, pa2, pa3, pb0, pb1, pb2, pb3;
#define NADE_STEP(PA, PB, AV, WV, XSA, XSB)                                    \
        {                                                                      \
            const float sa0 = __builtin_amdgcn_rcpf(1.0f + __builtin_amdgcn_exp2f(ua.x)); \
            const float sa1 = __builtin_amdgcn_rcpf(1.0f + __builtin_amdgcn_exp2f(ua.y)); \
            const float sa2 = __builtin_amdgcn_rcpf(1.0f + __builtin_amdgcn_exp2f(ua.z)); \
            const float sa3 = __builtin_amdgcn_rcpf(1.0f + __builtin_amdgcn_exp2f(ua.w)); \
            PA = fmaf(AV.w, sa3, fmaf(AV.z, sa2, fmaf(AV.y, sa1, AV.x * sa0))); \
            ua.x += fmaf(XSA, WV.x, bh2.x); ua.y += fmaf(XSA, WV.y, bh2.y);    \
            ua.z += fmaf(XSA, WV.z, bh2.z); ua.w += fmaf(XSA, WV.w, bh2.w);    \
            const float sb0 = __builtin_amdgcn_rcpf(1.0f + __builtin_amdgcn_exp2f(ub.x)); \
            const float sb1 = __builtin_amdgcn_rcpf(1.0f + __builtin_amdgcn_exp2f(ub.y)); \
            const float sb2 = __builtin_amdgcn_rcpf(1.0f + __builtin_amdgcn_exp2f(ub.z)); \
            const float sb3 = __builtin_amdgcn_rcpf(1.0f + __builtin_amdgcn_exp2f(ub.w)); \
            PB = fmaf(AV.w, sb3, fmaf(AV.z, sb2, fmaf(AV.y, sb1, AV.x * sb0))); \
            ub.x += fmaf(XSB, WV.x, bh2.x); ub.y += fmaf(XSB, WV.y, bh2.y);    \
            ub.z += fmaf(XSB, WV.z, bh2.z); ub.w += fmaf(XSB, WV.w, bh2.w);    \
        }
        NADE_STEP(pa0, pb0, a0, w0, x4a.x, x4b.x)  // sigmoid BEFORE update
        NADE_STEP(pa1, pb1, a1, w1, x4a.y, x4b.y)
        NADE_STEP(pa2, pb2, a2, w2, x4a.z, x4b.z)
        NADE_STEP(pa3, pb3, a3, w3, x4a.w, x4b.w)
#undef NADE_STEP

        // ======= reduce: DPP quad + select + DPP row + permlane swaps =======
        pa0 += dpp_mov<0xB1>(pa0); pa0 += dpp_mov<0x4E>(pa0);
        pa1 += dpp_mov<0xB1>(pa1); pa1 += dpp_mov<0x4E>(pa1);
        pa2 += dpp_mov<0xB1>(pa2); pa2 += dpp_mov<0x4E>(pa2);
        pa3 += dpp_mov<0xB1>(pa3); pa3 += dpp_mov<0x4E>(pa3);
        pb0 += dpp_mov<0xB1>(pb0); pb0 += dpp_mov<0x4E>(pb0);
        pb1 += dpp_mov<0xB1>(pb1); pb1 += dpp_mov<0x4E>(pb1);
        pb2 += dpp_mov<0xB1>(pb2); pb2 += dpp_mov<0x4E>(pb2);
        pb3 += dpp_mov<0xB1>(pb3); pb3 += dpp_mov<0x4E>(pb3);
        const float ta0_ = (lane & 1) ? pa1 : pa0;
        const float ta1_ = (lane & 1) ? pa3 : pa2;
        float qa = (lane & 2) ? ta1_ : ta0_;
        const float tb0_ = (lane & 1) ? pb1 : pb0;
        const float tb1_ = (lane & 1) ? pb3 : pb2;
        float qb = (lane & 2) ? tb1_ : tb0_;
        qa += dpp_mov<0x124>(qa);        // row_ror:4
        qa += dpp_mov<0x128>(qa);        // row_ror:8
        qa = xor16_add(qa);
        qa = xor32_add(qa);
        qb += dpp_mov<0x124>(qb);
        qb += dpp_mov<0x128>(qb);
        qb = xor16_add(qb);
        qb = xor32_add(qb);
        // q = full 256-h dot for i = c*LN + ii + j (replicated per class)
        const float sa = qa + abq;
        const float sb = qb + abq;
        const float lpa = -LN2 *
            __builtin_amdgcn_logf(1.0f + __builtin_amdgcn_exp2f(-sa * LOG2E));
        const float lpb = -LN2 *
            __builtin_amdgcn_logf(1.0f + __builtin_amdgcn_exp2f(-sb * LOG2E));
        Aa = fmaf(lpa, fmaf(2.0f, xqa, -1.0f), Aa);
        Ba += xqa;
        Ab = fmaf(lpb, fmaf(2.0f, xqb, -1.0f), Ab);
        Bb += xqb;
    }

    // each class replicated 16x across the wave
#pragma unroll
    for (int off = 32; off > 0; off >>= 1) {
        Aa += __shfl_xor(Aa, off, 64);
        Ba += __shfl_xor(Ba, off, 64);
        Ab += __shfl_xor(Ab, off, 64);
        Bb += __shfl_xor(Bb, off, 64);
    }
    if (lane == 0) {
        llp[(size_t)b0 * C + c] = (Aa - Ba) * (1.0f / 16.0f) + (float)LN;
        llp[(size_t)b1 * C + c] = (Ab - Bb) * (1.0f / 16.0f) + (float)LN;
    }
}

// ---------- pass 4: final reduce ----------
__global__ void final_kernel(const float* __restrict__ llp,
                             float* __restrict__ out, int Bn, int C) {
    const int b = blockIdx.x * blockDim.x + threadIdx.x;
    if (b < Bn) {
        float s = 0.f;
        for (int c = 0; c < C; ++c) s += llp[(size_t)b * C + c];
        out[b] = s;
    }
}

// ---------- fallback (round-1 style, unscaled) ----------
__global__ __launch_bounds__(64) void nade_fallback(
    const float* __restrict__ x, const float* __restrict__ Wh,
    const float* __restrict__ bh, const float* __restrict__ aw,
    const float* __restrict__ ab, float* __restrict__ out, int Dn, int Hn)
{
    const int b    = blockIdx.x;
    const int lane = threadIdx.x;
    const float* xrow = x + (size_t)b * Dn;
    float ll = 0.f;
    float accl[8];
    float bhl[8];
    for (int k = 0; k < 8; ++k) { accl[k] = 0.f; bhl[k] = 0.f; }
    const int hper = Hn / 64;
    for (int k = 0; k < hper && k < 8; ++k) bhl[k] = bh[lane * hper + k];
    for (int i = 0; i < Dn; ++i) {
        float pm = 0.f;
        for (int k = 0; k < hper && k < 8; ++k) {
            const int h = lane * hper + k;
            const float sg = __builtin_amdgcn_rcpf(
                1.0f + __builtin_amdgcn_exp2f(-accl[k] * LOG2E));
            pm = fmaf(aw[(size_t)i * Hn + h], sg, pm);
        }
        for (int off = 32; off > 0; off >>= 1) pm += __shfl_xor(pm, off, 64);
        const float s = pm + ab[i];
        const float lp = -LN2 *
            __builtin_amdgcn_logf(1.0f + __builtin_amdgcn_exp2f(-s * LOG2E));
        const float xv = xrow[i];
        ll += xv * lp + (1.0f - xv) * (1.0f - lp);
        for (int k = 0; k < hper && k < 8; ++k) {
            const int h = lane * hper + k;
            accl[k] = fmaf(xv, Wh[(size_t)h * Dn + i], accl[k]) + bhl[k];
        }
    }
    if (lane == 0) out[b] = ll;
}

extern "C" void kernel_launch(void* const* d_in, const int* in_sizes, int n_in,
                              void* d_out, int out_size, void* d_ws, size_t ws_size,
                              hipStream_t stream) {
    const float* x  = (const float*)d_in[0];
    const float* Wh = (const float*)d_in[1];
    const float* bh = (const float*)d_in[2];
    const float* aw = (const float*)d_in[3];
    const float* ab = (const float*)d_in[4];
    float* out = (float*)d_out;

    const int Bn = out_size;          // 1024
    const int Hn = in_sizes[2];       // 256
    const int Dn = in_sizes[4];       // 1024
    constexpr int HN = 256;
    constexpr int LN = 128;
    const int C = 8;

    const size_t wt_bytes  = (size_t)Dn * Hn * sizeof(float);
    const size_t pf_bytes  = (size_t)Bn * C * Hn * sizeof(float);
    const size_t llp_bytes = (size_t)Bn * C * sizeof(float);

    const bool shapes_ok = (Hn == HN) && (Dn == C * LN) && (Bn % 32 == 0);
    const bool full_path = shapes_ok && ws_size >= wt_bytes + pf_bytes + llp_bytes;

    if (full_path) {
        float* Wt2     = (float*)d_ws;
        float* partial = (float*)((char*)d_ws + wt_bytes);
        float* llp     = (float*)((char*)d_ws + wt_bytes + pf_bytes);

        transpose_kernel<<<dim3(Dn / 32, Hn / 32), dim3(32, 8), 0, stream>>>(
            Wh, Wt2, Hn, Dn, NLOG2E);
        partial_kernel<HN, LN><<<(Bn / 32) * C, 512, 0, stream>>>(
            x, Wt2, partial, Dn, Bn, C);
        nade_main<HN, LN><<<(Bn / 16) * C, 512, 0, stream>>>(
            x, Wt2, partial, bh, aw, ab, llp, Dn, Bn, C);
        final_kernel<<<(Bn + 255) / 256, 256, 0, stream>>>(llp, out, Bn, C);
    } else {
        nade_fallback<<<Bn, 64, 0, stream>>>(x, Wh, bh, aw, ab, out, Dn, Hn);
    }
}